// Round 10
// baseline (441.773 us; speedup 1.0000x reference)
//
#include <hip/hip_runtime.h>
#include <stdint.h>

#define T_SEQ 2048
#define D_MODEL 2048
#define N_KV 4
#define HD 128
#define QKV_W 3072   // fused row width: 2048 q | 512 k | 512 v

typedef unsigned short us;
typedef __attribute__((ext_vector_type(8))) short bf16x8;
typedef __attribute__((ext_vector_type(4))) float f32x4;
typedef __attribute__((ext_vector_type(8))) unsigned short u16x8;

__device__ __forceinline__ us f2bf(float f) {
  union { float f; unsigned int u; } v; v.f = f;
  unsigned int r = v.u + 0x7FFFu + ((v.u >> 16) & 1u);
  return (us)(r >> 16);
}
__device__ __forceinline__ float bf2f(us h) {
  union { unsigned int u; float f; } v; v.u = ((unsigned int)h) << 16;
  return v.f;
}

__device__ __forceinline__ void load_lds16(const void* g, void* l) {
  __builtin_amdgcn_global_load_lds(
      (const __attribute__((address_space(1))) void*)g,
      (__attribute__((address_space(3))) void*)l, 16, 0, 0);
}

__global__ void fill_diag(float* __restrict__ out, float val, int n) {
  int i = blockIdx.x * blockDim.x + threadIdx.x;
  if (i < n) out[i] = val;
}

// ---------------------------------------------------------------------------
__global__ void cast_f32_bf16(const float* __restrict__ src,
                              us* __restrict__ dst, int n8) {
  int i = blockIdx.x * blockDim.x + threadIdx.x;
  if (i >= n8) return;
  const float4* s = (const float4*)src + (size_t)i * 2;
  float4 a = s[0], b = s[1];
  u16x8 o;
  o[0] = f2bf(a.x); o[1] = f2bf(a.y); o[2] = f2bf(a.z); o[3] = f2bf(a.w);
  o[4] = f2bf(b.x); o[5] = f2bf(b.y); o[6] = f2bf(b.z); o[7] = f2bf(b.w);
  *((u16x8*)dst + i) = o;
}

// ---------------------------------------------------------------------------
// 8-phase 256x256 GEMM (m201 template, plain HIP): C[M][N] = A[M][K]*B[N][K]^T.
// BK=64 K-tiles, 2 tiles/iteration, 8 waves (2M x 4N), 512 thr, LDS 128KB.
// LDS stored as 16x32 subtiles (1024B = one wave gload_lds); st_16x32 swizzle
// (byte bit5 ^= bit9) applied on ds_read; inverse applied by PRE-PERMUTING the
// global source lane (s = lane^2 for lanes>=32) -> linear gload_lds dest.
// Counted vmcnt(6) at phases 4/8 only -- raw s_barrier (NO __syncthreads
// vmcnt(0) drain) keeps 14 staged loads in flight across barriers.
// Stage schedule (region's last read always >=1 barrier before stage issue):
//   P1: A-late(buf1,t+1)  P2: A-early(buf0,t+2)  P3: B-early  P4: B-late
//   P5: A-late(buf0,t+2)  P6: A-early(buf1,t+3)  P7: B-early  P8: B-late
// Drain math: at P4/P8, own-wave queue = 8 (current-need tile) + 6 (next) ->
// vmcnt(6) completes exactly the tile about to be read.
// ---------------------------------------------------------------------------
#define GBAR()                                  \
  do {                                          \
    asm volatile("" ::: "memory");              \
    __builtin_amdgcn_s_barrier();               \
    asm volatile("" ::: "memory");              \
  } while (0)
#define VMCNT6() asm volatile("s_waitcnt vmcnt(6)" ::: "memory")
#define VMCNT0() asm volatile("s_waitcnt vmcnt(0)" ::: "memory")

template <typename OUT>
__global__ __launch_bounds__(512) void gemm_bt8(
    const us* __restrict__ A, const us* __restrict__ B,
    OUT* __restrict__ C, int M, int N, int K) {
  __shared__ us As[2][16384];   // 256 rows x 64 K-cols as 16x32 subtiles
  __shared__ us Bs[2][16384];

  const int tid  = threadIdx.x;
  const int lane = tid & 63;
  const int wave = tid >> 6;          // 0..7
  const int wm   = wave & 1;          // M-half (128 rows)
  const int wn   = wave >> 1;         // N-quarter (64 cols)
  const int l15  = lane & 15;
  const int quad = lane >> 4;
  const int bm = blockIdx.x * 256;
  const int bn = blockIdx.y * 256;
  const int wm8 = wm * 8;
  const int wn4 = wn * 4;

  // reader offset within subtile (us), st_16x32: byte bit5 ^= row bit3
  const int ro = ((l15 << 5) | (quad << 3)) ^ ((l15 & 8) << 1);

  // writer source-lane permutation (inverse swizzle): lanes>=32 swap pairs
  const int s    = lane ^ ((lane & 32) >> 4);
  const int srow = s >> 2;
  const int schk = (s & 3) * 8;

  // per-wave staging rows (R = 16-row subtile index, 0..15)
  const int R_Ae = (wave & 3) | ((wave & 4) << 1);   // {0,1,2,3,8,9,10,11}
  const int R_Al = R_Ae + 4;                         // {4,5,6,7,12,13,14,15}
  const int R_Be = ((wave >> 1) << 2) | (wave & 1);  // {0,1,4,5,8,9,12,13}
  const int R_Bl = R_Be + 2;                         // {2,3,6,7,10,11,14,15}

  const us* Ab = A + (size_t)bm * K;
  const us* Bb = B + (size_t)bn * K;

  f32x4 acc[8][4];
#pragma unroll
  for (int i = 0; i < 8; i++)
#pragma unroll
    for (int j = 0; j < 4; j++) acc[i][j] = (f32x4)0.f;

  bf16x8 af[4][2], bf[4][2];

#define STG(DST, PG, R, KT)                                                   \
  do {                                                                        \
    load_lds16((PG) + (size_t)((R) * 16 + srow) * K + (KT) * 64 + schk,       \
               &(DST)[(((R) * 2 + 0) << 9) + (lane << 3)]);                   \
    load_lds16((PG) + (size_t)((R) * 16 + srow) * K + (KT) * 64 + 32 + schk,  \
               &(DST)[(((R) * 2 + 1) << 9) + (lane << 3)]);                   \
  } while (0)

#define LDA4(BUF, MTB)                                                        \
  _Pragma("unroll") for (int t = 0; t < 4; t++)                               \
      _Pragma("unroll") for (int ks = 0; ks < 2; ks++)                        \
          af[t][ks] = *(const bf16x8*)&As[BUF][(((wm8 + (MTB) + t) * 2 + ks)  \
                                               << 9) + ro];

#define LDB2(BUF, NTB)                                                        \
  _Pragma("unroll") for (int t = 0; t < 2; t++)                               \
      _Pragma("unroll") for (int ks = 0; ks < 2; ks++)                        \
          bf[(NTB) + t][ks] = *(const bf16x8*)&Bs[BUF][                       \
              (((wn4 + (NTB) + t) * 2 + ks) << 9) + ro];

#define MQ(MH, NB)                                                            \
  __builtin_amdgcn_s_setprio(1);                                              \
  _Pragma("unroll") for (int t = 0; t < 4; t++)                               \
      _Pragma("unroll") for (int u = 0; u < 2; u++)                           \
          _Pragma("unroll") for (int ks = 0; ks < 2; ks++)                    \
              acc[(MH) * 4 + t][(NB) + u] =                                   \
                  __builtin_amdgcn_mfma_f32_16x16x32_bf16(                    \
                      af[t][ks], bf[(NB) + u][ks],                            \
                      acc[(MH) * 4 + t][(NB) + u], 0, 0, 0);                  \
  __builtin_amdgcn_s_setprio(0);

  // prologue: tile0 -> buf0 (all 4 groups); tile1 -> buf1 (3 early groups;
  // A-late of tile1 is P1's job). Queue 14, vmcnt(6) -> tile0 complete.
  STG(As[0], Ab, R_Ae, 0); STG(As[0], Ab, R_Al, 0);
  STG(Bs[0], Bb, R_Be, 0); STG(Bs[0], Bb, R_Bl, 0);
  STG(As[1], Ab, R_Ae, 1); STG(Bs[1], Bb, R_Be, 1); STG(Bs[1], Bb, R_Bl, 1);
  VMCNT6();
  GBAR();

  const int NI = K >> 7;               // iterations of 2 K-tiles (128 K)
  for (int i = 0; i < NI - 1; i++) {
    const int t0 = 2 * i;
    // P1
    LDA4(0, 0) LDB2(0, 0)
    STG(As[1], Ab, R_Al, t0 + 1);
    GBAR(); MQ(0, 0) GBAR();
    // P2
    LDB2(0, 2)
    STG(As[0], Ab, R_Ae, t0 + 2);
    GBAR(); MQ(0, 2) GBAR();
    // P3
    LDA4(0, 4)
    STG(Bs[0], Bb, R_Be, t0 + 2);
    GBAR(); MQ(1, 2) GBAR();
    // P4
    STG(Bs[0], Bb, R_Bl, t0 + 2);
    GBAR(); MQ(1, 0) VMCNT6(); GBAR();
    // P5
    LDA4(1, 0) LDB2(1, 0)
    STG(As[0], Ab, R_Al, t0 + 2);
    GBAR(); MQ(0, 0) GBAR();
    // P6
    LDB2(1, 2)
    STG(As[1], Ab, R_Ae, t0 + 3);
    GBAR(); MQ(0, 2) GBAR();
    // P7
    LDA4(1, 4)
    STG(Bs[1], Bb, R_Be, t0 + 3);
    GBAR(); MQ(1, 2) GBAR();
    // P8
    STG(Bs[1], Bb, R_Bl, t0 + 3);
    GBAR(); MQ(1, 0) VMCNT6(); GBAR();
  }

  // peeled last iteration: only P1's A-late stage (tile 2NI-1) remains;
  // vmcnt(0) at P4 (queue holds exactly that tile's 8 loads).
  {
    const int t0 = 2 * NI - 2;
    LDA4(0, 0) LDB2(0, 0)
    STG(As[1], Ab, R_Al, t0 + 1);
    GBAR(); MQ(0, 0) GBAR();
    LDB2(0, 2)
    GBAR(); MQ(0, 2) GBAR();
    LDA4(0, 4)
    GBAR(); MQ(1, 2) GBAR();
    GBAR(); MQ(1, 0) VMCNT0(); GBAR();
    LDA4(1, 0) LDB2(1, 0)
    GBAR(); MQ(0, 0) GBAR();
    LDB2(1, 2)
    GBAR(); MQ(0, 2) GBAR();
    LDA4(1, 4)
    GBAR(); MQ(1, 2) GBAR();
    MQ(1, 0)
  }
#undef STG
#undef LDA4
#undef LDB2
#undef MQ

  // epilogue: C layout col = l15, row = quad*4 + r (verified m89/m91)
#pragma unroll
  for (int mt = 0; mt < 8; mt++) {
    int row = bm + wm * 128 + mt * 16 + quad * 4;
#pragma unroll
    for (int nt = 0; nt < 4; nt++) {
      int col = bn + wn * 64 + nt * 16 + l15;
#pragma unroll
      for (int r = 0; r < 4; r++) {
        if constexpr (sizeof(OUT) == 4)
          C[(size_t)(row + r) * N + col] = acc[mt][nt][r];
        else
          C[(size_t)(row + r) * N + col] = f2bf(acc[mt][nt][r]);
      }
    }
  }
}

// ---------------------------------------------------------------------------
// RoPE in-place on fused qkv [B*T][3072]: q heads at col h*128, k heads at
// col 2048 + hk*128. angle = t * 10000^(-i/64); pairs (i, i+64).
// ---------------------------------------------------------------------------
__global__ void rope_kernel(us* __restrict__ qkv) {
  const int row = blockIdx.x;
  const int t = row & (T_SEQ - 1);
  const int tid = threadIdx.x;
  const float L2_10K_64 = 13.287712379549449f / 64.f;
  us* rp = qkv + (size_t)row * QKV_W;

#pragma unroll
  for (int it = 0; it < 4; it++) {     // 16 q heads * 64 pairs
    int idx = it * 256 + tid;
    int h = idx >> 6, i = idx & 63;
    int base = h * HD;
    float ang = (float)t * exp2f(-(float)i * L2_10K_64);
    float s, c; sincosf(ang, &s, &c);
    float x1 = bf2f(rp[base + i]);
    float x2 = bf2f(rp[base + i + 64]);
    rp[base + i]      = f2bf(x1 * c - x2 * s);
    rp[base + i + 64] = f2bf(x2 * c + x1 * s);
  }
  {                                    // 4 k heads * 64 pairs
    int h = tid >> 6, i = tid & 63;
    int base = 2048 + h * HD;
    float ang = (float)t * exp2f(-(float)i * L2_10K_64);
    float s, c; sincosf(ang, &s, &c);
    float x1 = bf2f(rp[base + i]);
    float x2 = bf2f(rp[base + i + 64]);
    rp[base + i]      = f2bf(x1 * c - x2 * s);
    rp[base + i + 64] = f2bf(x2 * c + x1 * s);
  }
}

// ---------------------------------------------------------------------------
// Causal flash attention, GQA. EXACT R0 proven structure (197us in R7):
// block = pair of Q-tiles {31-p, p}, 64-key chunks, single Ks/Vt buffer,
// 2 barriers/chunk, register prefetch. Exact-math tweaks: base-2 softmax,
// deferred l-reduce, per-kh split Pl, setprio. Structural variants all
// regressed (R1-R5). Plain __launch_bounds__(256); min-waves arg spills.
// ---------------------------------------------------------------------------
__device__ __forceinline__ int vperm(int d) { return ((d >> 3) ^ d) & 7; }

__global__ __launch_bounds__(256) void attn_kernel(
    const us* __restrict__ qkv, us* __restrict__ y) {
  __shared__ us Ks[64][136];     // 128 data + 8 pad: 68 dwords/row
  __shared__ us Vt[128][64];     // V^T, XOR-swizzled 8-key blocks
  __shared__ us Pl[4][2][16][40]; // per-wave, per-kh-half P staging

  const int tid  = threadIdx.x;
  const int lane = tid & 63;
  const int wave = tid >> 6;
  const int l15  = lane & 15;
  const int quad = lane >> 4;
  const int p  = blockIdx.x;           // 0..15 -> tiles {31-p, p}
  const int bh = blockIdx.y;
  const int b  = bh >> 4;
  const int h  = bh & 15;
  const int hk = h >> 2;

  const us* base = qkv + (size_t)b * T_SEQ * QKV_W;
  const int kcol = 2048 + hk * HD;
  const int vcol = kcol + 512;
  const int skey = tid >> 4;           // 0..15
  const int skk  = (tid & 15) * 8;     // 0..120
  // scale * log2(e): softmax computed in base 2 (invariant)
  const float scale = 0.12751744f;     // 1/sqrt(128) * 1.4426950408889634

  for (int half = 0; half < 2; half++) {
    const int x  = half ? p : 31 - p;  // long tile first
    const int m0 = x * 64;

    bf16x8 qf[4];
    {
      const us* Qrow = base + (size_t)(m0 + wave * 16 + l15) * QKV_W + h * HD;
#pragma unroll
      for (int s = 0; s < 4; s++)
        qf[s] = *(const bf16x8*)&Qrow[s * 32 + quad * 8];
    }

    f32x4 O[8];
#pragma unroll
    for (int i = 0; i < 8; i++) O[i] = (f32x4)0.f;
    float mrun[4], lrun[4];
#pragma unroll
    for (int r = 0; r < 4; r++) { mrun[r] = -INFINITY; lrun[r] = 0.f; }

    // prefetch chunk 0
    uint4 kreg[4]; u16x8 vreg[4];
#pragma unroll
    for (int r = 0; r < 4; r++) {
      const us* row = base + (size_t)(skey + r * 16) * QKV_W;
      kreg[r] = *(const uint4*)(row + kcol + skk);
      vreg[r] = *(const u16x8*)(row + vcol + skk);
    }

    for (int j = 0; j <= x; j++) {
      __syncthreads();                 // prior chunk's LDS reads done
#pragma unroll
      for (int r = 0; r < 4; r++) {
        int key = skey + r * 16;
        *(uint4*)&Ks[key][skk] = kreg[r];
#pragma unroll
        for (int i = 0; i < 8; i++) {
          int d = skk + i;
          Vt[d][key ^ (vperm(d) << 3)] = vreg[r][i];
        }
      }
      __syncthreads();                 // staging visible

      if (j < x) {                     // prefetch next chunk (hidden by compute)
        const int k0n = (j + 1) * 64;
#pragma unroll
        for (int r = 0; r < 4; r++) {
          const us* row = base + (size_t)(k0n + skey + r * 16) * QKV_W;
          kreg[r] = *(const uint4*)(row + kcol + skk);
          vreg[r] = *(const u16x8*)(row + vcol + skk);
        }
      }

      // S = Q K^T
      f32x4 S[4];
      __builtin_amdgcn_s_setprio(1);
#pragma unroll
      for (int nt = 0; nt < 4; nt++) {
        f32x4 sa = (f32x4)0.f;
#pragma unroll
        for (int ks = 0; ks < 4; ks++) {
          bf16x8 kf = *(const bf16x8*)&Ks[nt * 16 + l15][ks * 32 + quad * 8];
          sa = __builtin_amdgcn_mfma_f32_16x16x32_bf16(qf[ks], kf, sa, 0, 0, 0);
        }
        S[nt] = sa;
      }
      __builtin_amdgcn_s_setprio(0);

      const int row0 = m0 + wave * 16 + quad * 4;
      if (j == x) {                    // diagonal chunk only: mask
        const int k0 = j * 64;
#pragma unroll
        for (int nt = 0; nt < 4; nt++) {
          int col = k0 + nt * 16 + l15;
#pragma unroll
          for (int r = 0; r < 4; r++) {
            float v = S[nt][r] * scale;
            if (col > row0 + r) v = -INFINITY;
            S[nt][r] = v;
          }
        }
      } else {
#pragma unroll
        for (int nt = 0; nt < 4; nt++)
#pragma unroll
          for (int r = 0; r < 4; r++) S[nt][r] *= scale;
      }

      // online softmax (base 2). lrun stays a per-lane partial (alpha is
      // uniform per 16-lane row group); cross-lane sum deferred to epilogue.
      float pr[4][4];
#pragma unroll
      for (int r = 0; r < 4; r++) {
        float mx = fmaxf(fmaxf(S[0][r], S[1][r]), fmaxf(S[2][r], S[3][r]));
#pragma unroll
        for (int off = 1; off < 16; off <<= 1)
          mx = fmaxf(mx, __shfl_xor(mx, off, 64));
        float mnew = fmaxf(mrun[r], mx);
        float alpha = exp2f(mrun[r] - mnew);
        mrun[r] = mnew;
        float sum = 0.f;
#pragma unroll
        for (int nt = 0; nt < 4; nt++) {
          float pv = exp2f(S[nt][r] - mnew);
          pr[nt][r] = pv;
          sum += pv;
        }
        lrun[r] = lrun[r] * alpha + sum;
#pragma unroll
        for (int ot = 0; ot < 8; ot++) O[ot][r] *= alpha;
      }

      // O += P V in two 32-key halves; per-kh Pl regions (no WAR stall).
      // Same-wave LDS write->read is program-ordered: no barrier needed.
#pragma unroll
      for (int kh = 0; kh < 2; kh++) {
#pragma unroll
        for (int nt = 0; nt < 2; nt++)
#pragma unroll
          for (int r = 0; r < 4; r++)
            Pl[wave][kh][quad * 4 + r][nt * 16 + l15] = f2bf(pr[kh * 2 + nt][r]);
        bf16x8 pf = *(const bf16x8*)&Pl[wave][kh][l15][quad * 8];
        __builtin_amdgcn_s_setprio(1);
#pragma unroll
        for (int ot = 0; ot < 8; ot++) {
          int dcol = ot * 16 + l15;
          bf16x8 vf = *(const bf16x8*)&Vt[dcol][(kh * 32 + quad * 8) ^ (vperm(dcol) << 3)];
          O[ot] = __builtin_amdgcn_mfma_f32_16x16x32_bf16(pf, vf, O[ot], 0, 0, 0);
        }
        __builtin_amdgcn_s_setprio(0);
      }
    }

    // epilogue: finish the deferred cross-lane l reduction, then write
    const int t_out = m0 + wave * 16 + quad * 4;
#pragma unroll
    for (int r = 0; r < 4; r++) {
      float s = lrun[r];
#pragma unroll
      for (int off = 1; off < 16; off <<= 1)
        s += __shfl_xor(s, off, 64);
      float inv_l = 1.f / s;
      us* yrow = y + (size_t)(b * T_SEQ + t_out + r) * D_MODEL + h * HD;
#pragma unroll
      for (int ot = 0; ot < 8; ot++)
        yrow[ot * 16 + l15] = f2bf(O[ot][r] * inv_l);
    }
  }
}

// ---------------------------------------------------------------------------
extern "C" void kernel_launch(void* const* d_in, const int* in_sizes, int n_in,
                              void* d_out, int out_size, void* d_ws, size_t ws_size,
                              hipStream_t stream) {
  const float* x     = (const float*)d_in[0];  // [2,2048,2048] fp32
  const float* Wq    = (const float*)d_in[1];  // [2048,2048]
  const float* Wkv   = (const float*)d_in[2];  // [1024,2048]
  const float* Wproj = (const float*)d_in[3];  // [2048,2048]
  float* out = (float*)d_out;                  // [2,2048,2048] fp32

  const size_t NX  = (size_t)4096 * 2048;
  const size_t NWQ = (size_t)2048 * 2048;
  const size_t NWK = (size_t)1024 * 2048;
  // ws (bf16): xb | Wqkvb (3072x2048) | Wpb | ybuf  = 54.6 MB
  const size_t needed_ws = (NX + (NWQ + NWK) + NWQ + NX) * sizeof(us);

  int b0 = (n_in >= 1 && (size_t)in_sizes[0] == NX);
  int b1 = (n_in >= 2 && (size_t)in_sizes[1] == NWQ);
  int b2 = (n_in >= 3 && (size_t)in_sizes[2] == NWK);
  int b3 = (n_in >= 4 && (size_t)in_sizes[3] == NWQ);
  int ws_ok = (ws_size >= needed_ws);
  int out_ok = ((size_t)out_size == NX);
  if (!(n_in == 4 && b0 && b1 && b2 && b3 && ws_ok && out_ok)) {
    float code = 1.0e6f * (float)(n_in < 10 ? n_in : 9)
               + 1.0e5f * b0 + 1.0e4f * b1 + 1.0e3f * b2 + 1.0e2f * b3
               + 10.0f * ws_ok + 40.0f * out_ok;
    fill_diag<<<dim3((out_size + 255) / 256), dim3(256), 0, stream>>>(out, code, out_size);
    return;
  }

  us* xb     = (us*)d_ws;
  us* Wqkvb  = xb + NX;            // [3072][2048]: rows 0-2047 Wq, 2048-3071 Wkv
  us* Wpb    = Wqkvb + NWQ + NWK;
  us* ybuf   = Wpb + NWQ;
  us* qkvbuf = (us*)d_out;         // [4096][3072] bf16 parks in d_out (25.2 of 33.6 MB);
                                   // dead before proj GEMM overwrites out with fp32.

  dim3 blk(256);
  cast_f32_bf16<<<dim3((int)(NX  / 8 / 256)), blk, 0, stream>>>(x,     xb,          (int)(NX  / 8));
  cast_f32_bf16<<<dim3((int)(NWQ / 8 / 256)), blk, 0, stream>>>(Wq,    Wqkvb,       (int)(NWQ / 8));
  cast_f32_bf16<<<dim3((int)(NWK / 8 / 256)), blk, 0, stream>>>(Wkv,   Wqkvb + NWQ, (int)(NWK / 8));
  cast_f32_bf16<<<dim3((int)(NWQ / 8 / 256)), blk, 0, stream>>>(Wproj, Wpb,         (int)(NWQ / 8));

  gemm_bt8<us><<<dim3(16, 12), dim3(512), 0, stream>>>(xb, Wqkvb, qkvbuf, 4096, 3072, 2048);
  rope_kernel<<<dim3(4096), blk, 0, stream>>>(qkvbuf);
  attn_kernel<<<dim3(16, 32), blk, 0, stream>>>(qkvbuf, ybuf);
  gemm_bt8<float><<<dim3(16, 8), dim3(512), 0, stream>>>(ybuf, Wpb, out, 4096, 2048, 2048);
}

// Round 11
// 423.925 us; speedup vs baseline: 1.0421x; 1.0421x over previous
//
#include <hip/hip_runtime.h>
#include <stdint.h>

#define T_SEQ 2048
#define D_MODEL 2048
#define N_KV 4
#define HD 128
#define QKV_W 3072   // fused row width: 2048 q | 512 k | 512 v

typedef unsigned short us;
typedef __attribute__((ext_vector_type(8))) short bf16x8;
typedef __attribute__((ext_vector_type(4))) float f32x4;
typedef __attribute__((ext_vector_type(8))) unsigned short u16x8;

__device__ __forceinline__ us f2bf(float f) {
  union { float f; unsigned int u; } v; v.f = f;
  unsigned int r = v.u + 0x7FFFu + ((v.u >> 16) & 1u);
  return (us)(r >> 16);
}
__device__ __forceinline__ float bf2f(us h) {
  union { unsigned int u; float f; } v; v.u = ((unsigned int)h) << 16;
  return v.f;
}

__device__ __forceinline__ void load_lds16(const void* g, void* l) {
  __builtin_amdgcn_global_load_lds(
      (const __attribute__((address_space(1))) void*)g,
      (__attribute__((address_space(3))) void*)l, 16, 0, 0);
}

__global__ void fill_diag(float* __restrict__ out, float val, int n) {
  int i = blockIdx.x * blockDim.x + threadIdx.x;
  if (i < n) out[i] = val;
}

// ---------------------------------------------------------------------------
__global__ void cast_f32_bf16(const float* __restrict__ src,
                              us* __restrict__ dst, int n8) {
  int i = blockIdx.x * blockDim.x + threadIdx.x;
  if (i >= n8) return;
  const float4* s = (const float4*)src + (size_t)i * 2;
  float4 a = s[0], b = s[1];
  u16x8 o;
  o[0] = f2bf(a.x); o[1] = f2bf(a.y); o[2] = f2bf(a.z); o[3] = f2bf(a.w);
  o[4] = f2bf(b.x); o[5] = f2bf(b.y); o[6] = f2bf(b.z); o[7] = f2bf(b.w);
  *((u16x8*)dst + i) = o;
}

// ---------------------------------------------------------------------------
// 2-phase 128x128 GEMM (proven R7, 412.7us config): double-buffered LDS,
// stage(t+1) issued BEFORE compute(t), ONE barrier per K-step. Full grid
// fill (512 blocks for N=2048) -- used for the proj GEMM where the 2562
// 8-phase tile gives only 128 blocks (half the machine idle, R10: +33us).
// ---------------------------------------------------------------------------
template <typename OUT>
__global__ __launch_bounds__(256) void gemm_bt(
    const us* __restrict__ A, const us* __restrict__ B,
    OUT* __restrict__ C, int M, int N, int K) {
  __shared__ us As[2][128 * 32];
  __shared__ us Bs[2][128 * 32];

  const int tid  = threadIdx.x;
  const int lane = tid & 63;
  const int wave = tid >> 6;
  const int l15  = lane & 15;
  const int quad = lane >> 4;
  const int bm = blockIdx.x * 128;
  const int bn = blockIdx.y * 128;
  const int wm = (wave & 1) * 64;
  const int wn = (wave >> 1) * 64;

  f32x4 acc[4][4];
#pragma unroll
  for (int i = 0; i < 4; i++)
#pragma unroll
    for (int j = 0; j < 4; j++) acc[i][j] = (f32x4)0.f;

  const int srow = tid >> 2;
  const int scol = (tid & 3) * 8;
  const us* Ag = A + (size_t)(bm + srow) * K + scol;
  const us* Bg = B + (size_t)(bn + srow) * K + scol;
  const size_t rowskip = (size_t)64 * K;

#define STAGE(buf, koff)                                            \
  do {                                                              \
    load_lds16(Ag + (koff), &As[(buf)][tid * 8]);                   \
    load_lds16(Ag + (koff) + rowskip, &As[(buf)][tid * 8 + 2048]);  \
    load_lds16(Bg + (koff), &Bs[(buf)][tid * 8]);                   \
    load_lds16(Bg + (koff) + rowskip, &Bs[(buf)][tid * 8 + 2048]);  \
  } while (0)

  STAGE(0, 0);
  __syncthreads();                     // vmcnt(0) drain: buf0 ready

  int cur = 0;
  for (int k0 = 0; k0 < K; k0 += 32) {
    if (k0 + 32 < K) STAGE(cur ^ 1, k0 + 32);  // overlaps compute below

    bf16x8 a[4], b[4];
#pragma unroll
    for (int mt = 0; mt < 4; mt++)
      a[mt] = *(const bf16x8*)&As[cur][(wm + mt * 16 + l15) * 32 + quad * 8];
#pragma unroll
    for (int nt = 0; nt < 4; nt++)
      b[nt] = *(const bf16x8*)&Bs[cur][(wn + nt * 16 + l15) * 32 + quad * 8];
#pragma unroll
    for (int mt = 0; mt < 4; mt++)
#pragma unroll
      for (int nt = 0; nt < 4; nt++)
        acc[mt][nt] = __builtin_amdgcn_mfma_f32_16x16x32_bf16(a[mt], b[nt], acc[mt][nt], 0, 0, 0);

    __syncthreads();                   // drains vmcnt(0): buf cur^1 staged
    cur ^= 1;
  }
#undef STAGE

#pragma unroll
  for (int mt = 0; mt < 4; mt++) {
    int row = bm + wm + mt * 16 + quad * 4;
#pragma unroll
    for (int nt = 0; nt < 4; nt++) {
      int col = bn + wn + nt * 16 + l15;
#pragma unroll
      for (int r = 0; r < 4; r++) {
        if constexpr (sizeof(OUT) == 4)
          C[(size_t)(row + r) * N + col] = acc[mt][nt][r];
        else
          C[(size_t)(row + r) * N + col] = f2bf(acc[mt][nt][r]);
      }
    }
  }
}

// ---------------------------------------------------------------------------
// 8-phase 256x256 GEMM (m201-style). Per-CU measured ~35% faster than the
// 2-phase kernel (R10 decomposition: 2.56 vs 1.9 TF/CU), but needs grid
// fill: used ONLY for the qkv GEMM (N=3072 -> 192 blocks, 75% fill, ~parity
// or better). R10 showed the proj GEMM (128 blocks, 50% fill) regresses.
// ---------------------------------------------------------------------------
#define GBAR()                                  \
  do {                                          \
    asm volatile("" ::: "memory");              \
    __builtin_amdgcn_s_barrier();               \
    asm volatile("" ::: "memory");              \
  } while (0)
#define VMCNT6() asm volatile("s_waitcnt vmcnt(6)" ::: "memory")
#define VMCNT0() asm volatile("s_waitcnt vmcnt(0)" ::: "memory")

template <typename OUT>
__global__ __launch_bounds__(512) void gemm_bt8(
    const us* __restrict__ A, const us* __restrict__ B,
    OUT* __restrict__ C, int M, int N, int K) {
  __shared__ us As[2][16384];   // 256 rows x 64 K-cols as 16x32 subtiles
  __shared__ us Bs[2][16384];

  const int tid  = threadIdx.x;
  const int lane = tid & 63;
  const int wave = tid >> 6;          // 0..7
  const int wm   = wave & 1;          // M-half (128 rows)
  const int wn   = wave >> 1;         // N-quarter (64 cols)
  const int l15  = lane & 15;
  const int quad = lane >> 4;
  const int bm = blockIdx.x * 256;
  const int bn = blockIdx.y * 256;
  const int wm8 = wm * 8;
  const int wn4 = wn * 4;

  // reader offset within subtile (us), st_16x32: byte bit5 ^= bit9
  const int ro = ((l15 << 5) | (quad << 3)) ^ ((l15 & 8) << 1);

  // writer source-lane permutation (inverse swizzle): lanes>=32 swap pairs
  const int s    = lane ^ ((lane & 32) >> 4);
  const int srow = s >> 2;
  const int schk = (s & 3) * 8;

  // per-wave staging rows (R = 16-row subtile index, 0..15)
  const int R_Ae = (wave & 3) | ((wave & 4) << 1);   // {0,1,2,3,8,9,10,11}
  const int R_Al = R_Ae + 4;                         // {4,5,6,7,12,13,14,15}
  const int R_Be = ((wave >> 1) << 2) | (wave & 1);  // {0,1,4,5,8,9,12,13}
  const int R_Bl = R_Be + 2;                         // {2,3,6,7,10,11,14,15}

  const us* Ab = A + (size_t)bm * K;
  const us* Bb = B + (size_t)bn * K;

  f32x4 acc[8][4];
#pragma unroll
  for (int i = 0; i < 8; i++)
#pragma unroll
    for (int j = 0; j < 4; j++) acc[i][j] = (f32x4)0.f;

  bf16x8 af[4][2], bf[4][2];

#define STG(DST, PG, R, KT)                                                   \
  do {                                                                        \
    load_lds16((PG) + (size_t)((R) * 16 + srow) * K + (KT) * 64 + schk,       \
               &(DST)[(((R) * 2 + 0) << 9) + (lane << 3)]);                   \
    load_lds16((PG) + (size_t)((R) * 16 + srow) * K + (KT) * 64 + 32 + schk,  \
               &(DST)[(((R) * 2 + 1) << 9) + (lane << 3)]);                   \
  } while (0)

#define LDA4(BUF, MTB)                                                        \
  _Pragma("unroll") for (int t = 0; t < 4; t++)                               \
      _Pragma("unroll") for (int ks = 0; ks < 2; ks++)                        \
          af[t][ks] = *(const bf16x8*)&As[BUF][(((wm8 + (MTB) + t) * 2 + ks)  \
                                               << 9) + ro];

#define LDB2(BUF, NTB)                                                        \
  _Pragma("unroll") for (int t = 0; t < 2; t++)                               \
      _Pragma("unroll") for (int ks = 0; ks < 2; ks++)                        \
          bf[(NTB) + t][ks] = *(const bf16x8*)&Bs[BUF][                       \
              (((wn4 + (NTB) + t) * 2 + ks) << 9) + ro];

#define MQ(MH, NB)                                                            \
  __builtin_amdgcn_s_setprio(1);                                              \
  _Pragma("unroll") for (int t = 0; t < 4; t++)                               \
      _Pragma("unroll") for (int u = 0; u < 2; u++)                           \
          _Pragma("unroll") for (int ks = 0; ks < 2; ks++)                    \
              acc[(MH) * 4 + t][(NB) + u] =                                   \
                  __builtin_amdgcn_mfma_f32_16x16x32_bf16(                    \
                      af[t][ks], bf[(NB) + u][ks],                            \
                      acc[(MH) * 4 + t][(NB) + u], 0, 0, 0);                  \
  __builtin_amdgcn_s_setprio(0);

  // prologue: tile0 -> buf0 (all 4 groups); tile1 -> buf1 (3 early groups).
  STG(As[0], Ab, R_Ae, 0); STG(As[0], Ab, R_Al, 0);
  STG(Bs[0], Bb, R_Be, 0); STG(Bs[0], Bb, R_Bl, 0);
  STG(As[1], Ab, R_Ae, 1); STG(Bs[1], Bb, R_Be, 1); STG(Bs[1], Bb, R_Bl, 1);
  VMCNT6();
  GBAR();

  const int NI = K >> 7;               // iterations of 2 K-tiles (128 K)
  for (int i = 0; i < NI - 1; i++) {
    const int t0 = 2 * i;
    // P1
    LDA4(0, 0) LDB2(0, 0)
    STG(As[1], Ab, R_Al, t0 + 1);
    GBAR(); MQ(0, 0) GBAR();
    // P2
    LDB2(0, 2)
    STG(As[0], Ab, R_Ae, t0 + 2);
    GBAR(); MQ(0, 2) GBAR();
    // P3
    LDA4(0, 4)
    STG(Bs[0], Bb, R_Be, t0 + 2);
    GBAR(); MQ(1, 2) GBAR();
    // P4
    STG(Bs[0], Bb, R_Bl, t0 + 2);
    GBAR(); MQ(1, 0) VMCNT6(); GBAR();
    // P5
    LDA4(1, 0) LDB2(1, 0)
    STG(As[0], Ab, R_Al, t0 + 2);
    GBAR(); MQ(0, 0) GBAR();
    // P6
    LDB2(1, 2)
    STG(As[1], Ab, R_Ae, t0 + 3);
    GBAR(); MQ(0, 2) GBAR();
    // P7
    LDA4(1, 4)
    STG(Bs[1], Bb, R_Be, t0 + 3);
    GBAR(); MQ(1, 2) GBAR();
    // P8
    STG(Bs[1], Bb, R_Bl, t0 + 3);
    GBAR(); MQ(1, 0) VMCNT6(); GBAR();
  }

  // peeled last iteration
  {
    const int t0 = 2 * NI - 2;
    LDA4(0, 0) LDB2(0, 0)
    STG(As[1], Ab, R_Al, t0 + 1);
    GBAR(); MQ(0, 0) GBAR();
    LDB2(0, 2)
    GBAR(); MQ(0, 2) GBAR();
    LDA4(0, 4)
    GBAR(); MQ(1, 2) GBAR();
    GBAR(); MQ(1, 0) VMCNT0(); GBAR();
    LDA4(1, 0) LDB2(1, 0)
    GBAR(); MQ(0, 0) GBAR();
    LDB2(1, 2)
    GBAR(); MQ(0, 2) GBAR();
    LDA4(1, 4)
    GBAR(); MQ(1, 2) GBAR();
    MQ(1, 0)
  }
#undef STG
#undef LDA4
#undef LDB2
#undef MQ

#pragma unroll
  for (int mt = 0; mt < 8; mt++) {
    int row = bm + wm * 128 + mt * 16 + quad * 4;
#pragma unroll
    for (int nt = 0; nt < 4; nt++) {
      int col = bn + wn * 64 + nt * 16 + l15;
#pragma unroll
      for (int r = 0; r < 4; r++) {
        if constexpr (sizeof(OUT) == 4)
          C[(size_t)(row + r) * N + col] = acc[mt][nt][r];
        else
          C[(size_t)(row + r) * N + col] = f2bf(acc[mt][nt][r]);
      }
    }
  }
}

// ---------------------------------------------------------------------------
// RoPE in-place on fused qkv [B*T][3072]: q heads at col h*128, k heads at
// col 2048 + hk*128. angle = t * 10000^(-i/64); pairs (i, i+64).
// ---------------------------------------------------------------------------
__global__ void rope_kernel(us* __restrict__ qkv) {
  const int row = blockIdx.x;
  const int t = row & (T_SEQ - 1);
  const int tid = threadIdx.x;
  const float L2_10K_64 = 13.287712379549449f / 64.f;
  us* rp = qkv + (size_t)row * QKV_W;

#pragma unroll
  for (int it = 0; it < 4; it++) {     // 16 q heads * 64 pairs
    int idx = it * 256 + tid;
    int h = idx >> 6, i = idx & 63;
    int base = h * HD;
    float ang = (float)t * exp2f(-(float)i * L2_10K_64);
    float s, c; sincosf(ang, &s, &c);
    float x1 = bf2f(rp[base + i]);
    float x2 = bf2f(rp[base + i + 64]);
    rp[base + i]      = f2bf(x1 * c - x2 * s);
    rp[base + i + 64] = f2bf(x2 * c + x1 * s);
  }
  {                                    // 4 k heads * 64 pairs
    int h = tid >> 6, i = tid & 63;
    int base = 2048 + h * HD;
    float ang = (float)t * exp2f(-(float)i * L2_10K_64);
    float s, c; sincosf(ang, &s, &c);
    float x1 = bf2f(rp[base + i]);
    float x2 = bf2f(rp[base + i + 64]);
    rp[base + i]      = f2bf(x1 * c - x2 * s);
    rp[base + i + 64] = f2bf(x2 * c + x1 * s);
  }
}

// ---------------------------------------------------------------------------
// Causal flash attention, GQA. EXACT R0 proven structure (196us): block =
// pair of Q-tiles {31-p, p}, 64-key chunks, single Ks/Vt buffer, 2 barriers/
// chunk, register prefetch. Exact-math tweaks: base-2 softmax, deferred
// l-reduce, per-kh split Pl, setprio. Structural variants all regressed
// (R1-R5). Plain __launch_bounds__(256); min-waves arg spills.
// ---------------------------------------------------------------------------
__device__ __forceinline__ int vperm(int d) { return ((d >> 3) ^ d) & 7; }

__global__ __launch_bounds__(256) void attn_kernel(
    const us* __restrict__ qkv, us* __restrict__ y) {
  __shared__ us Ks[64][136];     // 128 data + 8 pad: 68 dwords/row
  __shared__ us Vt[128][64];     // V^T, XOR-swizzled 8-key blocks
  __shared__ us Pl[4][2][16][40]; // per-wave, per-kh-half P staging

  const int tid  = threadIdx.x;
  const int lane = tid & 63;
  const int wave = tid >> 6;
  const int l15  = lane & 15;
  const int quad = lane >> 4;
  const int p  = blockIdx.x;           // 0..15 -> tiles {31-p, p}
  const int bh = blockIdx.y;
  const int b  = bh >> 4;
  const int h  = bh & 15;
  const int hk = h >> 2;

  const us* base = qkv + (size_t)b * T_SEQ * QKV_W;
  const int kcol = 2048 + hk * HD;
  const int vcol = kcol + 512;
  const int skey = tid >> 4;           // 0..15
  const int skk  = (tid & 15) * 8;     // 0..120
  // scale * log2(e): softmax computed in base 2 (invariant)
  const float scale = 0.12751744f;     // 1/sqrt(128) * 1.4426950408889634

  for (int half = 0; half < 2; half++) {
    const int x  = half ? p : 31 - p;  // long tile first
    const int m0 = x * 64;

    bf16x8 qf[4];
    {
      const us* Qrow = base + (size_t)(m0 + wave * 16 + l15) * QKV_W + h * HD;
#pragma unroll
      for (int s = 0; s < 4; s++)
        qf[s] = *(const bf16x8*)&Qrow[s * 32 + quad * 8];
    }

    f32x4 O[8];
#pragma unroll
    for (int i = 0; i < 8; i++) O[i] = (f32x4)0.f;
    float mrun[4], lrun[4];
#pragma unroll
    for (int r = 0; r < 4; r++) { mrun[r] = -INFINITY; lrun[r] = 0.f; }

    // prefetch chunk 0
    uint4 kreg[4]; u16x8 vreg[4];
#pragma unroll
    for (int r = 0; r < 4; r++) {
      const us* row = base + (size_t)(skey + r * 16) * QKV_W;
      kreg[r] = *(const uint4*)(row + kcol + skk);
      vreg[r] = *(const u16x8*)(row + vcol + skk);
    }

    for (int j = 0; j <= x; j++) {
      __syncthreads();                 // prior chunk's LDS reads done
#pragma unroll
      for (int r = 0; r < 4; r++) {
        int key = skey + r * 16;
        *(uint4*)&Ks[key][skk] = kreg[r];
#pragma unroll
        for (int i = 0; i < 8; i++) {
          int d = skk + i;
          Vt[d][key ^ (vperm(d) << 3)] = vreg[r][i];
        }
      }
      __syncthreads();                 // staging visible

      if (j < x) {                     // prefetch next chunk (hidden by compute)
        const int k0n = (j + 1) * 64;
#pragma unroll
        for (int r = 0; r < 4; r++) {
          const us* row = base + (size_t)(k0n + skey + r * 16) * QKV_W;
          kreg[r] = *(const uint4*)(row + kcol + skk);
          vreg[r] = *(const u16x8*)(row + vcol + skk);
        }
      }

      // S = Q K^T
      f32x4 S[4];
      __builtin_amdgcn_s_setprio(1);
#pragma unroll
      for (int nt = 0; nt < 4; nt++) {
        f32x4 sa = (f32x4)0.f;
#pragma unroll
        for (int ks = 0; ks < 4; ks++) {
          bf16x8 kf = *(const bf16x8*)&Ks[nt * 16 + l15][ks * 32 + quad * 8];
          sa = __builtin_amdgcn_mfma_f32_16x16x32_bf16(qf[ks], kf, sa, 0, 0, 0);
        }
        S[nt] = sa;
      }
      __builtin_amdgcn_s_setprio(0);

      const int row0 = m0 + wave * 16 + quad * 4;
      if (j == x) {                    // diagonal chunk only: mask
        const int k0 = j * 64;
#pragma unroll
        for (int nt = 0; nt < 4; nt++) {
          int col = k0 + nt * 16 + l15;
#pragma unroll
          for (int r = 0; r < 4; r++) {
            float v = S[nt][r] * scale;
            if (col > row0 + r) v = -INFINITY;
            S[nt][r] = v;
          }
        }
      } else {
#pragma unroll
        for (int nt = 0; nt < 4; nt++)
#pragma unroll
          for (int r = 0; r < 4; r++) S[nt][r] *= scale;
      }

      // online softmax (base 2). lrun stays a per-lane partial (alpha is
      // uniform per 16-lane row group); cross-lane sum deferred to epilogue.
      float pr[4][4];
#pragma unroll
      for (int r = 0; r < 4; r++) {
        float mx = fmaxf(fmaxf(S[0][r], S[1][r]), fmaxf(S[2][r], S[3][r]));
#pragma unroll
        for (int off = 1; off < 16; off <<= 1)
          mx = fmaxf(mx, __shfl_xor(mx, off, 64));
        float mnew = fmaxf(mrun[r], mx);
        float alpha = exp2f(mrun[r] - mnew);
        mrun[r] = mnew;
        float sum = 0.f;
#pragma unroll
        for (int nt = 0; nt < 4; nt++) {
          float pv = exp2f(S[nt][r] - mnew);
          pr[nt][r] = pv;
          sum += pv;
        }
        lrun[r] = lrun[r] * alpha + sum;
#pragma unroll
        for (int ot = 0; ot < 8; ot++) O[ot][r] *= alpha;
      }

      // O += P V in two 32-key halves; per-kh Pl regions (no WAR stall).
#pragma unroll
      for (int kh = 0; kh < 2; kh++) {
#pragma unroll
        for (int nt = 0; nt < 2; nt++)
#pragma unroll
          for (int r = 0; r < 4; r++)
            Pl[wave][kh][quad * 4 + r][nt * 16 + l15] = f2bf(pr[kh * 2 + nt][r]);
        bf16x8 pf = *(const bf16x8*)&Pl[wave][kh][l15][quad * 8];
        __builtin_amdgcn_s_setprio(1);
#pragma unroll
        for (int ot = 0; ot < 8; ot++) {
          int dcol = ot * 16 + l15;
          bf16x8 vf = *(const bf16x8*)&Vt[dcol][(kh * 32 + quad * 8) ^ (vperm(dcol) << 3)];
          O[ot] = __builtin_amdgcn_mfma_f32_16x16x32_bf16(pf, vf, O[ot], 0, 0, 0);
        }
        __builtin_amdgcn_s_setprio(0);
      }
    }

    // epilogue: finish the deferred cross-lane l reduction, then write
    const int t_out = m0 + wave * 16 + quad * 4;
#pragma unroll
    for (int r = 0; r < 4; r++) {
      float s = lrun[r];
#pragma unroll
      for (int off = 1; off < 16; off <<= 1)
        s += __shfl_xor(s, off, 64);
      float inv_l = 1.f / s;
      us* yrow = y + (size_t)(b * T_SEQ + t_out + r) * D_MODEL + h * HD;
#pragma unroll
      for (int ot = 0; ot < 8; ot++)
        yrow[ot * 16 + l15] = f2bf(O[ot][r] * inv_l);
    }
  }
}

// ---------------------------------------------------------------------------
extern "C" void kernel_launch(void* const* d_in, const int* in_sizes, int n_in,
                              void* d_out, int out_size, void* d_ws, size_t ws_size,
                              hipStream_t stream) {
  const float* x     = (const float*)d_in[0];  // [2,2048,2048] fp32
  const float* Wq    = (const float*)d_in[1];  // [2048,2048]
  const float* Wkv   = (const float*)d_in[2];  // [1024,2048]
  const float* Wproj = (const float*)d_in[3];  // [2048,2048]
  float* out = (float*)d_out;                  // [2,2048,2048] fp32

  const size_t NX  = (size_t)4096 * 2048;
  const size_t NWQ = (size_t)2048 * 2048;
  const size_t NWK = (size_t)1024 * 2048;
  // ws (bf16): xb | Wqkvb (3072x2048) | Wpb | ybuf  = 54.6 MB
  const size_t needed_ws = (NX + (NWQ + NWK) + NWQ + NX) * sizeof(us);

  int b0 = (n_in >= 1 && (size_t)in_sizes[0] == NX);
  int b1 = (n_in >= 2 && (size_t)in_sizes[1] == NWQ);
  int b2 = (n_in >= 3 && (size_t)in_sizes[2] == NWK);
  int b3 = (n_in >= 4 && (size_t)in_sizes[3] == NWQ);
  int ws_ok = (ws_size >= needed_ws);
  int out_ok = ((size_t)out_size == NX);
  if (!(n_in == 4 && b0 && b1 && b2 && b3 && ws_ok && out_ok)) {
    float code = 1.0e6f * (float)(n_in < 10 ? n_in : 9)
               + 1.0e5f * b0 + 1.0e4f * b1 + 1.0e3f * b2 + 1.0e2f * b3
               + 10.0f * ws_ok + 40.0f * out_ok;
    fill_diag<<<dim3((out_size + 255) / 256), dim3(256), 0, stream>>>(out, code, out_size);
    return;
  }

  us* xb     = (us*)d_ws;
  us* Wqkvb  = xb + NX;            // [3072][2048]: rows 0-2047 Wq, 2048-3071 Wkv
  us* Wpb    = Wqkvb + NWQ + NWK;
  us* ybuf   = Wpb + NWQ;
  us* qkvbuf = (us*)d_out;         // [4096][3072] bf16 parks in d_out (25.2 of 33.6 MB);
                                   // dead before proj GEMM overwrites out with fp32.

  dim3 blk(256);
  cast_f32_bf16<<<dim3((int)(NX  / 8 / 256)), blk, 0, stream>>>(x,     xb,          (int)(NX  / 8));
  cast_f32_bf16<<<dim3((int)(NWQ / 8 / 256)), blk, 0, stream>>>(Wq,    Wqkvb,       (int)(NWQ / 8));
  cast_f32_bf16<<<dim3((int)(NWK / 8 / 256)), blk, 0, stream>>>(Wkv,   Wqkvb + NWQ, (int)(NWK / 8));
  cast_f32_bf16<<<dim3((int)(NWQ / 8 / 256)), blk, 0, stream>>>(Wproj, Wpb,         (int)(NWQ / 8));

  // qkv GEMM: 8-phase 256^2 (192 blocks, 75% fill -- per-CU faster).
  gemm_bt8<us><<<dim3(16, 12), dim3(512), 0, stream>>>(xb, Wqkvb, qkvbuf, 4096, 3072, 2048);
  rope_kernel<<<dim3(4096), blk, 0, stream>>>(qkvbuf);
  attn_kernel<<<dim3(16, 32), blk, 0, stream>>>(qkvbuf, ybuf);
  // proj GEMM: 2-phase 128^2 (512 blocks, full fill -- R10: 256^2 tile
  // gives only 128 blocks and loses 33us to idle CUs).
  gemm_bt<float><<<dim3(32, 16), blk, 0, stream>>>(ybuf, Wpb, out, 4096, 2048, 2048);
}

// Round 13
// 392.620 us; speedup vs baseline: 1.1252x; 1.0797x over previous
//
#include <hip/hip_runtime.h>
#include <stdint.h>

#define T_SEQ 2048
#define D_MODEL 2048
#define N_KV 4
#define HD 128
#define QKV_W 3072   // fused row width: 2048 q | 512 k | 512 v

typedef unsigned short us;
typedef __attribute__((ext_vector_type(8))) short bf16x8;
typedef __attribute__((ext_vector_type(4))) float f32x4;
typedef __attribute__((ext_vector_type(8))) unsigned short u16x8;

__device__ __forceinline__ us f2bf(float f) {
  union { float f; unsigned int u; } v; v.f = f;
  unsigned int r = v.u + 0x7FFFu + ((v.u >> 16) & 1u);
  return (us)(r >> 16);
}
__device__ __forceinline__ float bf2f(us h) {
  union { unsigned int u; float f; } v; v.u = ((unsigned int)h) << 16;
  return v.f;
}

__device__ __forceinline__ void load_lds16(const void* g, void* l) {
  __builtin_amdgcn_global_load_lds(
      (const __attribute__((address_space(1))) void*)g,
      (__attribute__((address_space(3))) void*)l, 16, 0, 0);
}

__global__ void fill_diag(float* __restrict__ out, float val, int n) {
  int i = blockIdx.x * blockDim.x + threadIdx.x;
  if (i < n) out[i] = val;
}

// ---------------------------------------------------------------------------
__global__ void cast_f32_bf16(const float* __restrict__ src,
                              us* __restrict__ dst, int n8) {
  int i = blockIdx.x * blockDim.x + threadIdx.x;
  if (i >= n8) return;
  const float4* s = (const float4*)src + (size_t)i * 2;
  float4 a = s[0], b = s[1];
  u16x8 o;
  o[0] = f2bf(a.x); o[1] = f2bf(a.y); o[2] = f2bf(a.z); o[3] = f2bf(a.w);
  o[4] = f2bf(b.x); o[5] = f2bf(b.y); o[6] = f2bf(b.z); o[7] = f2bf(b.w);
  *((u16x8*)dst + i) = o;
}

// ---------------------------------------------------------------------------
// 2-phase 128x128 GEMM (proven R7): double-buffered LDS, stage(t+1) issued
// BEFORE compute(t), ONE barrier per K-step. Used for proj GEMM (full fill).
// ---------------------------------------------------------------------------
template <typename OUT>
__global__ __launch_bounds__(256) void gemm_bt(
    const us* __restrict__ A, const us* __restrict__ B,
    OUT* __restrict__ C, int M, int N, int K) {
  __shared__ us As[2][128 * 32];
  __shared__ us Bs[2][128 * 32];

  const int tid  = threadIdx.x;
  const int lane = tid & 63;
  const int wave = tid >> 6;
  const int l15  = lane & 15;
  const int quad = lane >> 4;
  const int bm = blockIdx.x * 128;
  const int bn = blockIdx.y * 128;
  const int wm = (wave & 1) * 64;
  const int wn = (wave >> 1) * 64;

  f32x4 acc[4][4];
#pragma unroll
  for (int i = 0; i < 4; i++)
#pragma unroll
    for (int j = 0; j < 4; j++) acc[i][j] = (f32x4)0.f;

  const int srow = tid >> 2;
  const int scol = (tid & 3) * 8;
  const us* Ag = A + (size_t)(bm + srow) * K + scol;
  const us* Bg = B + (size_t)(bn + srow) * K + scol;
  const size_t rowskip = (size_t)64 * K;

#define STAGE(buf, koff)                                            \
  do {                                                              \
    load_lds16(Ag + (koff), &As[(buf)][tid * 8]);                   \
    load_lds16(Ag + (koff) + rowskip, &As[(buf)][tid * 8 + 2048]);  \
    load_lds16(Bg + (koff), &Bs[(buf)][tid * 8]);                   \
    load_lds16(Bg + (koff) + rowskip, &Bs[(buf)][tid * 8 + 2048]);  \
  } while (0)

  STAGE(0, 0);
  __syncthreads();

  int cur = 0;
  for (int k0 = 0; k0 < K; k0 += 32) {
    if (k0 + 32 < K) STAGE(cur ^ 1, k0 + 32);

    bf16x8 a[4], b[4];
#pragma unroll
    for (int mt = 0; mt < 4; mt++)
      a[mt] = *(const bf16x8*)&As[cur][(wm + mt * 16 + l15) * 32 + quad * 8];
#pragma unroll
    for (int nt = 0; nt < 4; nt++)
      b[nt] = *(const bf16x8*)&Bs[cur][(wn + nt * 16 + l15) * 32 + quad * 8];
#pragma unroll
    for (int mt = 0; mt < 4; mt++)
#pragma unroll
      for (int nt = 0; nt < 4; nt++)
        acc[mt][nt] = __builtin_amdgcn_mfma_f32_16x16x32_bf16(a[mt], b[nt], acc[mt][nt], 0, 0, 0);

    __syncthreads();
    cur ^= 1;
  }
#undef STAGE

#pragma unroll
  for (int mt = 0; mt < 4; mt++) {
    int row = bm + wm + mt * 16 + quad * 4;
#pragma unroll
    for (int nt = 0; nt < 4; nt++) {
      int col = bn + wn + nt * 16 + l15;
#pragma unroll
      for (int r = 0; r < 4; r++) {
        if constexpr (sizeof(OUT) == 4)
          C[(size_t)(row + r) * N + col] = acc[mt][nt][r];
        else
          C[(size_t)(row + r) * N + col] = f2bf(acc[mt][nt][r]);
      }
    }
  }
}

// ---------------------------------------------------------------------------
// 8-phase 256x256 GEMM. Per-CU ~35% faster than 2-phase (R10 decomposition)
// but needs grid fill: used ONLY for qkv GEMM (192 blocks, 75% fill; R11:
// -7us vs 2-phase). proj GEMM (128 blocks, 50% fill) regressed (R10).
// ---------------------------------------------------------------------------
#define GBAR()                                  \
  do {                                          \
    asm volatile("" ::: "memory");              \
    __builtin_amdgcn_s_barrier();               \
    asm volatile("" ::: "memory");              \
  } while (0)
#define VMCNT6() asm volatile("s_waitcnt vmcnt(6)" ::: "memory")
#define VMCNT0() asm volatile("s_waitcnt vmcnt(0)" ::: "memory")

template <typename OUT>
__global__ __launch_bounds__(512) void gemm_bt8(
    const us* __restrict__ A, const us* __restrict__ B,
    OUT* __restrict__ C, int M, int N, int K) {
  __shared__ us As[2][16384];
  __shared__ us Bs[2][16384];

  const int tid  = threadIdx.x;
  const int lane = tid & 63;
  const int wave = tid >> 6;
  const int wm   = wave & 1;
  const int wn   = wave >> 1;
  const int l15  = lane & 15;
  const int quad = lane >> 4;
  const int bm = blockIdx.x * 256;
  const int bn = blockIdx.y * 256;
  const int wm8 = wm * 8;
  const int wn4 = wn * 4;

  const int ro = ((l15 << 5) | (quad << 3)) ^ ((l15 & 8) << 1);

  const int s    = lane ^ ((lane & 32) >> 4);
  const int srow = s >> 2;
  const int schk = (s & 3) * 8;

  const int R_Ae = (wave & 3) | ((wave & 4) << 1);
  const int R_Al = R_Ae + 4;
  const int R_Be = ((wave >> 1) << 2) | (wave & 1);
  const int R_Bl = R_Be + 2;

  const us* Ab = A + (size_t)bm * K;
  const us* Bb = B + (size_t)bn * K;

  f32x4 acc[8][4];
#pragma unroll
  for (int i = 0; i < 8; i++)
#pragma unroll
    for (int j = 0; j < 4; j++) acc[i][j] = (f32x4)0.f;

  bf16x8 af[4][2], bf[4][2];

#define STG(DST, PG, R, KT)                                                   \
  do {                                                                        \
    load_lds16((PG) + (size_t)((R) * 16 + srow) * K + (KT) * 64 + schk,       \
               &(DST)[(((R) * 2 + 0) << 9) + (lane << 3)]);                   \
    load_lds16((PG) + (size_t)((R) * 16 + srow) * K + (KT) * 64 + 32 + schk,  \
               &(DST)[(((R) * 2 + 1) << 9) + (lane << 3)]);                   \
  } while (0)

#define LDA4(BUF, MTB)                                                        \
  _Pragma("unroll") for (int t = 0; t < 4; t++)                               \
      _Pragma("unroll") for (int ks = 0; ks < 2; ks++)                        \
          af[t][ks] = *(const bf16x8*)&As[BUF][(((wm8 + (MTB) + t) * 2 + ks)  \
                                               << 9) + ro];

#define LDB2(BUF, NTB)                                                        \
  _Pragma("unroll") for (int t = 0; t < 2; t++)                               \
      _Pragma("unroll") for (int ks = 0; ks < 2; ks++)                        \
          bf[(NTB) + t][ks] = *(const bf16x8*)&Bs[BUF][                       \
              (((wn4 + (NTB) + t) * 2 + ks) << 9) + ro];

#define MQ(MH, NB)                                                            \
  __builtin_amdgcn_s_setprio(1);                                              \
  _Pragma("unroll") for (int t = 0; t < 4; t++)                               \
      _Pragma("unroll") for (int u = 0; u < 2; u++)                           \
          _Pragma("unroll") for (int ks = 0; ks < 2; ks++)                    \
              acc[(MH) * 4 + t][(NB) + u] =                                   \
                  __builtin_amdgcn_mfma_f32_16x16x32_bf16(                    \
                      af[t][ks], bf[(NB) + u][ks],                            \
                      acc[(MH) * 4 + t][(NB) + u], 0, 0, 0);                  \
  __builtin_amdgcn_s_setprio(0);

  STG(As[0], Ab, R_Ae, 0); STG(As[0], Ab, R_Al, 0);
  STG(Bs[0], Bb, R_Be, 0); STG(Bs[0], Bb, R_Bl, 0);
  STG(As[1], Ab, R_Ae, 1); STG(Bs[1], Bb, R_Be, 1); STG(Bs[1], Bb, R_Bl, 1);
  VMCNT6();
  GBAR();

  const int NI = K >> 7;
  for (int i = 0; i < NI - 1; i++) {
    const int t0 = 2 * i;
    LDA4(0, 0) LDB2(0, 0)
    STG(As[1], Ab, R_Al, t0 + 1);
    GBAR(); MQ(0, 0) GBAR();
    LDB2(0, 2)
    STG(As[0], Ab, R_Ae, t0 + 2);
    GBAR(); MQ(0, 2) GBAR();
    LDA4(0, 4)
    STG(Bs[0], Bb, R_Be, t0 + 2);
    GBAR(); MQ(1, 2) GBAR();
    STG(Bs[0], Bb, R_Bl, t0 + 2);
    GBAR(); MQ(1, 0) VMCNT6(); GBAR();
    LDA4(1, 0) LDB2(1, 0)
    STG(As[0], Ab, R_Al, t0 + 2);
    GBAR(); MQ(0, 0) GBAR();
    LDB2(1, 2)
    STG(As[1], Ab, R_Ae, t0 + 3);
    GBAR(); MQ(0, 2) GBAR();
    LDA4(1, 4)
    STG(Bs[1], Bb, R_Be, t0 + 3);
    GBAR(); MQ(1, 2) GBAR();
    STG(Bs[1], Bb, R_Bl, t0 + 3);
    GBAR(); MQ(1, 0) VMCNT6(); GBAR();
  }
  {
    const int t0 = 2 * NI - 2;
    LDA4(0, 0) LDB2(0, 0)
    STG(As[1], Ab, R_Al, t0 + 1);
    GBAR(); MQ(0, 0) GBAR();
    LDB2(0, 2)
    GBAR(); MQ(0, 2) GBAR();
    LDA4(0, 4)
    GBAR(); MQ(1, 2) GBAR();
    GBAR(); MQ(1, 0) VMCNT0(); GBAR();
    LDA4(1, 0) LDB2(1, 0)
    GBAR(); MQ(0, 0) GBAR();
    LDB2(1, 2)
    GBAR(); MQ(0, 2) GBAR();
    LDA4(1, 4)
    GBAR(); MQ(1, 2) GBAR();
    MQ(1, 0)
  }
#undef STG
#undef LDA4
#undef LDB2
#undef MQ

#pragma unroll
  for (int mt = 0; mt < 8; mt++) {
    int row = bm + wm * 128 + mt * 16 + quad * 4;
#pragma unroll
    for (int nt = 0; nt < 4; nt++) {
      int col = bn + wn * 64 + nt * 16 + l15;
#pragma unroll
      for (int r = 0; r < 4; r++) {
        if constexpr (sizeof(OUT) == 4)
          C[(size_t)(row + r) * N + col] = acc[mt][nt][r];
        else
          C[(size_t)(row + r) * N + col] = f2bf(acc[mt][nt][r]);
      }
    }
  }
}

// ---------------------------------------------------------------------------
// RoPE in-place on fused qkv [B*T][3072].
// ---------------------------------------------------------------------------
__global__ void rope_kernel(us* __restrict__ qkv) {
  const int row = blockIdx.x;
  const int t = row & (T_SEQ - 1);
  const int tid = threadIdx.x;
  const float L2_10K_64 = 13.287712379549449f / 64.f;
  us* rp = qkv + (size_t)row * QKV_W;

#pragma unroll
  for (int it = 0; it < 4; it++) {
    int idx = it * 256 + tid;
    int h = idx >> 6, i = idx & 63;
    int base = h * HD;
    float ang = (float)t * exp2f(-(float)i * L2_10K_64);
    float s, c; sincosf(ang, &s, &c);
    float x1 = bf2f(rp[base + i]);
    float x2 = bf2f(rp[base + i + 64]);
    rp[base + i]      = f2bf(x1 * c - x2 * s);
    rp[base + i + 64] = f2bf(x2 * c + x1 * s);
  }
  {
    int h = tid >> 6, i = tid & 63;
    int base = 2048 + h * HD;
    float ang = (float)t * exp2f(-(float)i * L2_10K_64);
    float s, c; sincosf(ang, &s, &c);
    float x1 = bf2f(rp[base + i]);
    float x2 = bf2f(rp[base + i + 64]);
    rp[base + i]      = f2bf(x1 * c - x2 * s);
    rp[base + i + 64] = f2bf(x2 * c + x1 * s);
  }
}

// ---------------------------------------------------------------------------
// Causal flash attention, GQA -- CONCURRENT tile pairing. 512 threads:
// waves 0-3 own tile xA = 31-p (16 q-rows each), waves 4-7 own tile xB = p,
// both consuming ONE shared K/V chunk stream (same b,hk). Chunk-steps per
// block = xA+1 = 32-p (vs 33 serial in the R0 structure): each staged 16KB
// chunk feeds 128 q-rows instead of 64. p = blockIdx.x ^ (b*15): under
// round-robin dispatch CU c gets blocks c and c+256 (b differs) -> p and
// p^15 -> per-CU steps (32-p)+(17+p) = 49 uniform (was 66; -26%).
// Inner per-wave math byte-identical to the proven R0 kernel (QK, mask at
// j==x_mine, base-2 online softmax, deferred l-reduce, per-kh Pl, setprio).
// Compute guard (j <= x_mine) is wave-uniform; barriers unconditional.
// Per-thread staging halves -> kreg[2]/vreg[2] (-16 VGPR): target <=128 VGPR
// so 2 blocks/CU fit. Plain launch_bounds (min-waves arg spills, R1/R2).
// ---------------------------------------------------------------------------
__device__ __forceinline__ int vperm(int d) { return ((d >> 3) ^ d) & 7; }

__global__ __launch_bounds__(512) void attn_kernel(
    const us* __restrict__ qkv, us* __restrict__ y) {
  __shared__ us Ks[64][136];      // 128 data + 8 pad: 68 dwords/row
  __shared__ us Vt[128][64];      // V^T, XOR-swizzled 8-key blocks
  __shared__ us Pl[8][2][16][40]; // per-wave, per-kh-half P staging

  const int tid  = threadIdx.x;
  const int lane = tid & 63;
  const int wave = tid >> 6;           // 0..7
  const int l15  = lane & 15;
  const int quad = lane >> 4;
  const int bh = blockIdx.y;
  const int b  = bh >> 4;
  const int h  = bh & 15;
  const int hk = h >> 2;
  // complementary pairing: co-resident blocks (ids differing by 256 -> b
  // differs) get p and p^15 -> uniform 49 steps/CU under round-robin.
  const int p  = blockIdx.x ^ (b * 15);
  const int xA = 31 - p;               // waves 0-3 (long tile)
  const int xB = p;                    // waves 4-7 (short tile)
  const int x_mine = (wave < 4) ? xA : xB;
  const int m0 = x_mine * 64;
  const int w4 = wave & 3;

  const us* base = qkv + (size_t)b * T_SEQ * QKV_W;
  const int kcol = 2048 + hk * HD;
  const int vcol = kcol + 512;
  const int skey = tid >> 4;           // 0..31
  const int skk  = (tid & 15) * 8;     // 0..120
  const float scale = 0.12751744f;     // 1/sqrt(128) * log2(e)

  bf16x8 qf[4];
  {
    const us* Qrow = base + (size_t)(m0 + w4 * 16 + l15) * QKV_W + h * HD;
#pragma unroll
    for (int s = 0; s < 4; s++)
      qf[s] = *(const bf16x8*)&Qrow[s * 32 + quad * 8];
  }

  f32x4 O[8];
#pragma unroll
  for (int i = 0; i < 8; i++) O[i] = (f32x4)0.f;
  float mrun[4], lrun[4];
#pragma unroll
  for (int r = 0; r < 4; r++) { mrun[r] = -INFINITY; lrun[r] = 0.f; }

  // prefetch chunk 0 (64 keys over 512 threads: 2 key-rows per thread)
  uint4 kreg[2]; u16x8 vreg[2];
#pragma unroll
  for (int r = 0; r < 2; r++) {
    const us* row = base + (size_t)(skey + r * 32) * QKV_W;
    kreg[r] = *(const uint4*)(row + kcol + skk);
    vreg[r] = *(const u16x8*)(row + vcol + skk);
  }

  for (int j = 0; j <= xA; j++) {
    __syncthreads();                 // prior chunk's LDS reads done
#pragma unroll
    for (int r = 0; r < 2; r++) {
      int key = skey + r * 32;
      *(uint4*)&Ks[key][skk] = kreg[r];
#pragma unroll
      for (int i = 0; i < 8; i++) {
        int d = skk + i;
        Vt[d][key ^ (vperm(d) << 3)] = vreg[r][i];
      }
    }
    __syncthreads();                 // staging visible

    if (j < xA) {                    // prefetch next chunk (hidden by compute)
      const int k0n = (j + 1) * 64;
#pragma unroll
      for (int r = 0; r < 2; r++) {
        const us* row = base + (size_t)(k0n + skey + r * 32) * QKV_W;
        kreg[r] = *(const uint4*)(row + kcol + skk);
        vreg[r] = *(const u16x8*)(row + vcol + skk);
      }
    }

    if (j <= x_mine) {               // wave-uniform guard; barriers outside
      // S = Q K^T
      f32x4 S[4];
      __builtin_amdgcn_s_setprio(1);
#pragma unroll
      for (int nt = 0; nt < 4; nt++) {
        f32x4 sa = (f32x4)0.f;
#pragma unroll
        for (int ks = 0; ks < 4; ks++) {
          bf16x8 kf = *(const bf16x8*)&Ks[nt * 16 + l15][ks * 32 + quad * 8];
          sa = __builtin_amdgcn_mfma_f32_16x16x32_bf16(qf[ks], kf, sa, 0, 0, 0);
        }
        S[nt] = sa;
      }
      __builtin_amdgcn_s_setprio(0);

      const int row0 = m0 + w4 * 16 + quad * 4;
      if (j == x_mine) {             // diagonal chunk only: mask
        const int k0 = j * 64;
#pragma unroll
        for (int nt = 0; nt < 4; nt++) {
          int col = k0 + nt * 16 + l15;
#pragma unroll
          for (int r = 0; r < 4; r++) {
            float v = S[nt][r] * scale;
            if (col > row0 + r) v = -INFINITY;
            S[nt][r] = v;
          }
        }
      } else {
#pragma unroll
        for (int nt = 0; nt < 4; nt++)
#pragma unroll
          for (int r = 0; r < 4; r++) S[nt][r] *= scale;
      }

      // online softmax (base 2); lrun = per-lane partial, reduced in epilogue
      float pr[4][4];
#pragma unroll
      for (int r = 0; r < 4; r++) {
        float mx = fmaxf(fmaxf(S[0][r], S[1][r]), fmaxf(S[2][r], S[3][r]));
#pragma unroll
        for (int off = 1; off < 16; off <<= 1)
          mx = fmaxf(mx, __shfl_xor(mx, off, 64));
        float mnew = fmaxf(mrun[r], mx);
        float alpha = exp2f(mrun[r] - mnew);
        mrun[r] = mnew;
        float sum = 0.f;
#pragma unroll
        for (int nt = 0; nt < 4; nt++) {
          float pv = exp2f(S[nt][r] - mnew);
          pr[nt][r] = pv;
          sum += pv;
        }
        lrun[r] = lrun[r] * alpha + sum;
#pragma unroll
        for (int ot = 0; ot < 8; ot++) O[ot][r] *= alpha;
      }

      // O += P V in two 32-key halves; per-kh Pl regions (no WAR stall).
#pragma unroll
      for (int kh = 0; kh < 2; kh++) {
#pragma unroll
        for (int nt = 0; nt < 2; nt++)
#pragma unroll
          for (int r = 0; r < 4; r++)
            Pl[wave][kh][quad * 4 + r][nt * 16 + l15] = f2bf(pr[kh * 2 + nt][r]);
        bf16x8 pf = *(const bf16x8*)&Pl[wave][kh][l15][quad * 8];
        __builtin_amdgcn_s_setprio(1);
#pragma unroll
        for (int ot = 0; ot < 8; ot++) {
          int dcol = ot * 16 + l15;
          bf16x8 vf = *(const bf16x8*)&Vt[dcol][(kh * 32 + quad * 8) ^ (vperm(dcol) << 3)];
          O[ot] = __builtin_amdgcn_mfma_f32_16x16x32_bf16(pf, vf, O[ot], 0, 0, 0);
        }
        __builtin_amdgcn_s_setprio(0);
      }
    }
  }

  // epilogue: finish the deferred cross-lane l reduction, then write
  const int t_out = m0 + w4 * 16 + quad * 4;
#pragma unroll
  for (int r = 0; r < 4; r++) {
    float s = lrun[r];
#pragma unroll
    for (int off = 1; off < 16; off <<= 1)
      s += __shfl_xor(s, off, 64);
    float inv_l = 1.f / s;
    us* yrow = y + (size_t)(b * T_SEQ + t_out + r) * D_MODEL + h * HD;
#pragma unroll
    for (int ot = 0; ot < 8; ot++)
      yrow[ot * 16 + l15] = f2bf(O[ot][r] * inv_l);
  }
}

// ---------------------------------------------------------------------------
extern "C" void kernel_launch(void* const* d_in, const int* in_sizes, int n_in,
                              void* d_out, int out_size, void* d_ws, size_t ws_size,
                              hipStream_t stream) {
  const float* x     = (const float*)d_in[0];  // [2,2048,2048] fp32
  const float* Wq    = (const float*)d_in[1];  // [2048,2048]
  const float* Wkv   = (const float*)d_in[2];  // [1024,2048]
  const float* Wproj = (const float*)d_in[3];  // [2048,2048]
  float* out = (float*)d_out;                  // [2,2048,2048] fp32

  const size_t NX  = (size_t)4096 * 2048;
  const size_t NWQ = (size_t)2048 * 2048;
  const size_t NWK = (size_t)1024 * 2048;
  const size_t needed_ws = (NX + (NWQ + NWK) + NWQ + NX) * sizeof(us);

  int b0 = (n_in >= 1 && (size_t)in_sizes[0] == NX);
  int b1 = (n_in >= 2 && (size_t)in_sizes[1] == NWQ);
  int b2 = (n_in >= 3 && (size_t)in_sizes[2] == NWK);
  int b3 = (n_in >= 4 && (size_t)in_sizes[3] == NWQ);
  int ws_ok = (ws_size >= needed_ws);
  int out_ok = ((size_t)out_size == NX);
  if (!(n_in == 4 && b0 && b1 && b2 && b3 && ws_ok && out_ok)) {
    float code = 1.0e6f * (float)(n_in < 10 ? n_in : 9)
               + 1.0e5f * b0 + 1.0e4f * b1 + 1.0e3f * b2 + 1.0e2f * b3
               + 10.0f * ws_ok + 40.0f * out_ok;
    fill_diag<<<dim3((out_size + 255) / 256), dim3(256), 0, stream>>>(out, code, out_size);
    return;
  }

  us* xb     = (us*)d_ws;
  us* Wqkvb  = xb + NX;            // [3072][2048]: rows 0-2047 Wq, 2048-3071 Wkv
  us* Wpb    = Wqkvb + NWQ + NWK;
  us* ybuf   = Wpb + NWQ;
  us* qkvbuf = (us*)d_out;         // bf16 qkv parks in d_out; dead before proj

  dim3 blk(256);
  cast_f32_bf16<<<dim3((int)(NX  / 8 / 256)), blk, 0, stream>>>(x,     xb,          (int)(NX  / 8));
  cast_f32_bf16<<<dim3((int)(NWQ / 8 / 256)), blk, 0, stream>>>(Wq,    Wqkvb,       (int)(NWQ / 8));
  cast_f32_bf16<<<dim3((int)(NWK / 8 / 256)), blk, 0, stream>>>(Wkv,   Wqkvb + NWQ, (int)(NWK / 8));
  cast_f32_bf16<<<dim3((int)(NWQ / 8 / 256)), blk, 0, stream>>>(Wproj, Wpb,         (int)(NWQ / 8));

  // qkv GEMM: 8-phase 256^2 (192 blocks, 75% fill -- per-CU faster, R11 -7us)
  gemm_bt8<us><<<dim3(16, 12), dim3(512), 0, stream>>>(xb, Wqkvb, qkvbuf, 4096, 3072, 2048);
  rope_kernel<<<dim3(4096), blk, 0, stream>>>(qkvbuf);
  // attn: concurrent tile pairing, 512 threads
  attn_kernel<<<dim3(16, 32), dim3(512), 0, stream>>>(qkvbuf, ybuf);
  // proj GEMM: 2-phase 128^2 (512 blocks, full fill)
  gemm_bt<float><<<dim3(32, 16), blk, 0, stream>>>(ybuf, Wpb, out, 4096, 2048, 2048);
}

// Round 14
// 338.682 us; speedup vs baseline: 1.3044x; 1.1593x over previous
//
#include <hip/hip_runtime.h>
#include <stdint.h>

#define T_SEQ 2048
#define D_MODEL 2048
#define N_KV 4
#define HD 128
#define QKV_W 3072   // fused row width: 2048 q | 512 k | 512 v

typedef unsigned short us;
typedef __attribute__((ext_vector_type(8))) short bf16x8;
typedef __attribute__((ext_vector_type(4))) float f32x4;
typedef __attribute__((ext_vector_type(8))) unsigned short u16x8;

__device__ __forceinline__ us f2bf(float f) {
  union { float f; unsigned int u; } v; v.f = f;
  unsigned int r = v.u + 0x7FFFu + ((v.u >> 16) & 1u);
  return (us)(r >> 16);
}
__device__ __forceinline__ float bf2f(us h) {
  union { unsigned int u; float f; } v; v.u = ((unsigned int)h) << 16;
  return v.f;
}

__device__ __forceinline__ void load_lds16(const void* g, void* l) {
  __builtin_amdgcn_global_load_lds(
      (const __attribute__((address_space(1))) void*)g,
      (__attribute__((address_space(3))) void*)l, 16, 0, 0);
}

__global__ void fill_diag(float* __restrict__ out, float val, int n) {
  int i = blockIdx.x * blockDim.x + threadIdx.x;
  if (i < n) out[i] = val;
}

// ---------------------------------------------------------------------------
__global__ void cast_f32_bf16(const float* __restrict__ src,
                              us* __restrict__ dst, int n8) {
  int i = blockIdx.x * blockDim.x + threadIdx.x;
  if (i >= n8) return;
  const float4* s = (const float4*)src + (size_t)i * 2;
  float4 a = s[0], b = s[1];
  u16x8 o;
  o[0] = f2bf(a.x); o[1] = f2bf(a.y); o[2] = f2bf(a.z); o[3] = f2bf(a.w);
  o[4] = f2bf(b.x); o[5] = f2bf(b.y); o[6] = f2bf(b.z); o[7] = f2bf(b.w);
  *((u16x8*)dst + i) = o;
}

// ---------------------------------------------------------------------------
// 2-phase 128x128 GEMM (proven R7): double-buffered LDS, stage(t+1) issued
// BEFORE compute(t), ONE barrier per K-step. Used for proj GEMM (full fill).
// ---------------------------------------------------------------------------
template <typename OUT>
__global__ __launch_bounds__(256) void gemm_bt(
    const us* __restrict__ A, const us* __restrict__ B,
    OUT* __restrict__ C, int M, int N, int K) {
  __shared__ us As[2][128 * 32];
  __shared__ us Bs[2][128 * 32];

  const int tid  = threadIdx.x;
  const int lane = tid & 63;
  const int wave = tid >> 6;
  const int l15  = lane & 15;
  const int quad = lane >> 4;
  const int bm = blockIdx.x * 128;
  const int bn = blockIdx.y * 128;
  const int wm = (wave & 1) * 64;
  const int wn = (wave >> 1) * 64;

  f32x4 acc[4][4];
#pragma unroll
  for (int i = 0; i < 4; i++)
#pragma unroll
    for (int j = 0; j < 4; j++) acc[i][j] = (f32x4)0.f;

  const int srow = tid >> 2;
  const int scol = (tid & 3) * 8;
  const us* Ag = A + (size_t)(bm + srow) * K + scol;
  const us* Bg = B + (size_t)(bn + srow) * K + scol;
  const size_t rowskip = (size_t)64 * K;

#define STAGE(buf, koff)                                            \
  do {                                                              \
    load_lds16(Ag + (koff), &As[(buf)][tid * 8]);                   \
    load_lds16(Ag + (koff) + rowskip, &As[(buf)][tid * 8 + 2048]);  \
    load_lds16(Bg + (koff), &Bs[(buf)][tid * 8]);                   \
    load_lds16(Bg + (koff) + rowskip, &Bs[(buf)][tid * 8 + 2048]);  \
  } while (0)

  STAGE(0, 0);
  __syncthreads();

  int cur = 0;
  for (int k0 = 0; k0 < K; k0 += 32) {
    if (k0 + 32 < K) STAGE(cur ^ 1, k0 + 32);

    bf16x8 a[4], b[4];
#pragma unroll
    for (int mt = 0; mt < 4; mt++)
      a[mt] = *(const bf16x8*)&As[cur][(wm + mt * 16 + l15) * 32 + quad * 8];
#pragma unroll
    for (int nt = 0; nt < 4; nt++)
      b[nt] = *(const bf16x8*)&Bs[cur][(wn + nt * 16 + l15) * 32 + quad * 8];
#pragma unroll
    for (int mt = 0; mt < 4; mt++)
#pragma unroll
      for (int nt = 0; nt < 4; nt++)
        acc[mt][nt] = __builtin_amdgcn_mfma_f32_16x16x32_bf16(a[mt], b[nt], acc[mt][nt], 0, 0, 0);

    __syncthreads();
    cur ^= 1;
  }
#undef STAGE

#pragma unroll
  for (int mt = 0; mt < 4; mt++) {
    int row = bm + wm + mt * 16 + quad * 4;
#pragma unroll
    for (int nt = 0; nt < 4; nt++) {
      int col = bn + wn + nt * 16 + l15;
#pragma unroll
      for (int r = 0; r < 4; r++) {
        if constexpr (sizeof(OUT) == 4)
          C[(size_t)(row + r) * N + col] = acc[mt][nt][r];
        else
          C[(size_t)(row + r) * N + col] = f2bf(acc[mt][nt][r]);
      }
    }
  }
}

// ---------------------------------------------------------------------------
// 8-phase 256x256 GEMM. Per-CU ~35% faster than 2-phase (R10 decomposition)
// but needs grid fill: used ONLY for qkv GEMM (192 blocks, 75% fill; R11:
// -7us vs 2-phase). proj GEMM (128 blocks, 50% fill) regressed (R10).
// ---------------------------------------------------------------------------
#define GBAR()                                  \
  do {                                          \
    asm volatile("" ::: "memory");              \
    __builtin_amdgcn_s_barrier();               \
    asm volatile("" ::: "memory");              \
  } while (0)
#define VMCNT6() asm volatile("s_waitcnt vmcnt(6)" ::: "memory")
#define VMCNT0() asm volatile("s_waitcnt vmcnt(0)" ::: "memory")

template <typename OUT>
__global__ __launch_bounds__(512) void gemm_bt8(
    const us* __restrict__ A, const us* __restrict__ B,
    OUT* __restrict__ C, int M, int N, int K) {
  __shared__ us As[2][16384];
  __shared__ us Bs[2][16384];

  const int tid  = threadIdx.x;
  const int lane = tid & 63;
  const int wave = tid >> 6;
  const int wm   = wave & 1;
  const int wn   = wave >> 1;
  const int l15  = lane & 15;
  const int quad = lane >> 4;
  const int bm = blockIdx.x * 256;
  const int bn = blockIdx.y * 256;
  const int wm8 = wm * 8;
  const int wn4 = wn * 4;

  const int ro = ((l15 << 5) | (quad << 3)) ^ ((l15 & 8) << 1);

  const int s    = lane ^ ((lane & 32) >> 4);
  const int srow = s >> 2;
  const int schk = (s & 3) * 8;

  const int R_Ae = (wave & 3) | ((wave & 4) << 1);
  const int R_Al = R_Ae + 4;
  const int R_Be = ((wave >> 1) << 2) | (wave & 1);
  const int R_Bl = R_Be + 2;

  const us* Ab = A + (size_t)bm * K;
  const us* Bb = B + (size_t)bn * K;

  f32x4 acc[8][4];
#pragma unroll
  for (int i = 0; i < 8; i++)
#pragma unroll
    for (int j = 0; j < 4; j++) acc[i][j] = (f32x4)0.f;

  bf16x8 af[4][2], bf[4][2];

#define STG(DST, PG, R, KT)                                                   \
  do {                                                                        \
    load_lds16((PG) + (size_t)((R) * 16 + srow) * K + (KT) * 64 + schk,       \
               &(DST)[(((R) * 2 + 0) << 9) + (lane << 3)]);                   \
    load_lds16((PG) + (size_t)((R) * 16 + srow) * K + (KT) * 64 + 32 + schk,  \
               &(DST)[(((R) * 2 + 1) << 9) + (lane << 3)]);                   \
  } while (0)

#define LDA4(BUF, MTB)                                                        \
  _Pragma("unroll") for (int t = 0; t < 4; t++)                               \
      _Pragma("unroll") for (int ks = 0; ks < 2; ks++)                        \
          af[t][ks] = *(const bf16x8*)&As[BUF][(((wm8 + (MTB) + t) * 2 + ks)  \
                                               << 9) + ro];

#define LDB2(BUF, NTB)                                                        \
  _Pragma("unroll") for (int t = 0; t < 2; t++)                               \
      _Pragma("unroll") for (int ks = 0; ks < 2; ks++)                        \
          bf[(NTB) + t][ks] = *(const bf16x8*)&Bs[BUF][                       \
              (((wn4 + (NTB) + t) * 2 + ks) << 9) + ro];

#define MQ(MH, NB)                                                            \
  __builtin_amdgcn_s_setprio(1);                                              \
  _Pragma("unroll") for (int t = 0; t < 4; t++)                               \
      _Pragma("unroll") for (int u = 0; u < 2; u++)                           \
          _Pragma("unroll") for (int ks = 0; ks < 2; ks++)                    \
              acc[(MH) * 4 + t][(NB) + u] =                                   \
                  __builtin_amdgcn_mfma_f32_16x16x32_bf16(                    \
                      af[t][ks], bf[(NB) + u][ks],                            \
                      acc[(MH) * 4 + t][(NB) + u], 0, 0, 0);                  \
  __builtin_amdgcn_s_setprio(0);

  STG(As[0], Ab, R_Ae, 0); STG(As[0], Ab, R_Al, 0);
  STG(Bs[0], Bb, R_Be, 0); STG(Bs[0], Bb, R_Bl, 0);
  STG(As[1], Ab, R_Ae, 1); STG(Bs[1], Bb, R_Be, 1); STG(Bs[1], Bb, R_Bl, 1);
  VMCNT6();
  GBAR();

  const int NI = K >> 7;
  for (int i = 0; i < NI - 1; i++) {
    const int t0 = 2 * i;
    LDA4(0, 0) LDB2(0, 0)
    STG(As[1], Ab, R_Al, t0 + 1);
    GBAR(); MQ(0, 0) GBAR();
    LDB2(0, 2)
    STG(As[0], Ab, R_Ae, t0 + 2);
    GBAR(); MQ(0, 2) GBAR();
    LDA4(0, 4)
    STG(Bs[0], Bb, R_Be, t0 + 2);
    GBAR(); MQ(1, 2) GBAR();
    STG(Bs[0], Bb, R_Bl, t0 + 2);
    GBAR(); MQ(1, 0) VMCNT6(); GBAR();
    LDA4(1, 0) LDB2(1, 0)
    STG(As[0], Ab, R_Al, t0 + 2);
    GBAR(); MQ(0, 0) GBAR();
    LDB2(1, 2)
    STG(As[1], Ab, R_Ae, t0 + 3);
    GBAR(); MQ(0, 2) GBAR();
    LDA4(1, 4)
    STG(Bs[1], Bb, R_Be, t0 + 3);
    GBAR(); MQ(1, 2) GBAR();
    STG(Bs[1], Bb, R_Bl, t0 + 3);
    GBAR(); MQ(1, 0) VMCNT6(); GBAR();
  }
  {
    const int t0 = 2 * NI - 2;
    LDA4(0, 0) LDB2(0, 0)
    STG(As[1], Ab, R_Al, t0 + 1);
    GBAR(); MQ(0, 0) GBAR();
    LDB2(0, 2)
    GBAR(); MQ(0, 2) GBAR();
    LDA4(0, 4)
    GBAR(); MQ(1, 2) GBAR();
    GBAR(); MQ(1, 0) VMCNT0(); GBAR();
    LDA4(1, 0) LDB2(1, 0)
    GBAR(); MQ(0, 0) GBAR();
    LDB2(1, 2)
    GBAR(); MQ(0, 2) GBAR();
    LDA4(1, 4)
    GBAR(); MQ(1, 2) GBAR();
    MQ(1, 0)
  }
#undef STG
#undef LDA4
#undef LDB2
#undef MQ

#pragma unroll
  for (int mt = 0; mt < 8; mt++) {
    int row = bm + wm * 128 + mt * 16 + quad * 4;
#pragma unroll
    for (int nt = 0; nt < 4; nt++) {
      int col = bn + wn * 64 + nt * 16 + l15;
#pragma unroll
      for (int r = 0; r < 4; r++) {
        if constexpr (sizeof(OUT) == 4)
          C[(size_t)(row + r) * N + col] = acc[mt][nt][r];
        else
          C[(size_t)(row + r) * N + col] = f2bf(acc[mt][nt][r]);
      }
    }
  }
}

// ---------------------------------------------------------------------------
// RoPE in-place on fused qkv [B*T][3072].
// ---------------------------------------------------------------------------
__global__ void rope_kernel(us* __restrict__ qkv) {
  const int row = blockIdx.x;
  const int t = row & (T_SEQ - 1);
  const int tid = threadIdx.x;
  const float L2_10K_64 = 13.287712379549449f / 64.f;
  us* rp = qkv + (size_t)row * QKV_W;

#pragma unroll
  for (int it = 0; it < 4; it++) {
    int idx = it * 256 + tid;
    int h = idx >> 6, i = idx & 63;
    int base = h * HD;
    float ang = (float)t * exp2f(-(float)i * L2_10K_64);
    float s, c; sincosf(ang, &s, &c);
    float x1 = bf2f(rp[base + i]);
    float x2 = bf2f(rp[base + i + 64]);
    rp[base + i]      = f2bf(x1 * c - x2 * s);
    rp[base + i + 64] = f2bf(x2 * c + x1 * s);
  }
  {
    int h = tid >> 6, i = tid & 63;
    int base = 2048 + h * HD;
    float ang = (float)t * exp2f(-(float)i * L2_10K_64);
    float s, c; sincosf(ang, &s, &c);
    float x1 = bf2f(rp[base + i]);
    float x2 = bf2f(rp[base + i + 64]);
    rp[base + i]      = f2bf(x1 * c - x2 * s);
    rp[base + i + 64] = f2bf(x2 * c + x1 * s);
  }
}

// ---------------------------------------------------------------------------
// Causal flash attention, GQA -- FOUR-tile merge, 1024 threads, 1 block/CU.
// Wave-group g = wave>>2 owns tile: g0=31-p, g1=p, g2=15-p, g3=16+p
// (p = blockIdx.x in 0..7; bijective over 32 tiles). All four consume ONE
// shared 64-key K/V chunk stream: each staged 16KB chunk feeds 256 q-rows.
// Per-CU chunk-steps: 32-p in {25..32} (R13 2-tile pairing: 49; R0: 66).
// This extends the PROVEN R13 lever (fewer barrier-coupled steps/CU,
// attn 196->163) one level further. Inner per-wave math byte-identical.
// Grid 8x32 = 256 blocks = 1/CU. LDS 74.8KB. launch_bounds(1024) caps
// VGPR at 128 (needed for 16-wave launch); natural set ~100 -> no spill
// expected (R1/R2 spills were from over-capping BELOW the natural set).
// Tile guard (j <= x_mine) is wave-uniform; barriers unconditional.
// ---------------------------------------------------------------------------
__device__ __forceinline__ int vperm(int d) { return ((d >> 3) ^ d) & 7; }

__global__ __launch_bounds__(1024) void attn_kernel(
    const us* __restrict__ qkv, us* __restrict__ y) {
  __shared__ us Ks[64][136];       // 128 data + 8 pad: 68 dwords/row
  __shared__ us Vt[128][64];       // V^T, XOR-swizzled 8-key blocks
  __shared__ us Pl[16][2][16][40]; // per-wave, per-kh-half P staging

  const int tid  = threadIdx.x;
  const int lane = tid & 63;
  const int wave = tid >> 6;           // 0..15
  const int l15  = lane & 15;
  const int quad = lane >> 4;
  const int bh = blockIdx.y;
  const int b  = bh >> 4;
  const int h  = bh & 15;
  const int hk = h >> 2;
  const int p  = blockIdx.x;           // 0..7
  const int g  = wave >> 2;            // tile group 0..3
  const int w4 = wave & 3;
  const int xA = 31 - p;               // longest tile in this block
  // branchless tile select (no runtime-indexed array -> no scratch)
  const int x_mine = (g == 0) ? (31 - p)
                   : (g == 1) ? p
                   : (g == 2) ? (15 - p)
                              : (16 + p);
  const int m0 = x_mine * 64;

  const us* base = qkv + (size_t)b * T_SEQ * QKV_W;
  const int kcol = 2048 + hk * HD;
  const int vcol = kcol + 512;
  const int skey = tid >> 4;           // 0..63: one key-row per 16 threads
  const int skk  = (tid & 15) * 8;     // 0..120
  const float scale = 0.12751744f;     // 1/sqrt(128) * log2(e)

  bf16x8 qf[4];
  {
    const us* Qrow = base + (size_t)(m0 + w4 * 16 + l15) * QKV_W + h * HD;
#pragma unroll
    for (int s = 0; s < 4; s++)
      qf[s] = *(const bf16x8*)&Qrow[s * 32 + quad * 8];
  }

  f32x4 O[8];
#pragma unroll
  for (int i = 0; i < 8; i++) O[i] = (f32x4)0.f;
  float mrun[4], lrun[4];
#pragma unroll
  for (int r = 0; r < 4; r++) { mrun[r] = -INFINITY; lrun[r] = 0.f; }

  // prefetch chunk 0 (64 keys over 1024 threads: 1 key-row per thread-group)
  uint4 kreg; u16x8 vreg;
  {
    const us* row = base + (size_t)skey * QKV_W;
    kreg = *(const uint4*)(row + kcol + skk);
    vreg = *(const u16x8*)(row + vcol + skk);
  }

  for (int j = 0; j <= xA; j++) {
    __syncthreads();                 // prior chunk's LDS reads done
    *(uint4*)&Ks[skey][skk] = kreg;
#pragma unroll
    for (int i = 0; i < 8; i++) {
      int d = skk + i;
      Vt[d][skey ^ (vperm(d) << 3)] = vreg[i];
    }
    __syncthreads();                 // staging visible

    if (j < xA) {                    // prefetch next chunk (hidden by compute)
      const us* row = base + (size_t)((j + 1) * 64 + skey) * QKV_W;
      kreg = *(const uint4*)(row + kcol + skk);
      vreg = *(const u16x8*)(row + vcol + skk);
    }

    if (j <= x_mine) {               // wave-uniform guard; barriers outside
      // S = Q K^T
      f32x4 S[4];
      __builtin_amdgcn_s_setprio(1);
#pragma unroll
      for (int nt = 0; nt < 4; nt++) {
        f32x4 sa = (f32x4)0.f;
#pragma unroll
        for (int ks = 0; ks < 4; ks++) {
          bf16x8 kf = *(const bf16x8*)&Ks[nt * 16 + l15][ks * 32 + quad * 8];
          sa = __builtin_amdgcn_mfma_f32_16x16x32_bf16(qf[ks], kf, sa, 0, 0, 0);
        }
        S[nt] = sa;
      }
      __builtin_amdgcn_s_setprio(0);

      const int row0 = m0 + w4 * 16 + quad * 4;
      if (j == x_mine) {             // diagonal chunk only: mask
        const int k0 = j * 64;
#pragma unroll
        for (int nt = 0; nt < 4; nt++) {
          int col = k0 + nt * 16 + l15;
#pragma unroll
          for (int r = 0; r < 4; r++) {
            float v = S[nt][r] * scale;
            if (col > row0 + r) v = -INFINITY;
            S[nt][r] = v;
          }
        }
      } else {
#pragma unroll
        for (int nt = 0; nt < 4; nt++)
#pragma unroll
          for (int r = 0; r < 4; r++) S[nt][r] *= scale;
      }

      // online softmax (base 2); lrun = per-lane partial, reduced in epilogue
      float pr[4][4];
#pragma unroll
      for (int r = 0; r < 4; r++) {
        float mx = fmaxf(fmaxf(S[0][r], S[1][r]), fmaxf(S[2][r], S[3][r]));
#pragma unroll
        for (int off = 1; off < 16; off <<= 1)
          mx = fmaxf(mx, __shfl_xor(mx, off, 64));
        float mnew = fmaxf(mrun[r], mx);
        float alpha = exp2f(mrun[r] - mnew);
        mrun[r] = mnew;
        float sum = 0.f;
#pragma unroll
        for (int nt = 0; nt < 4; nt++) {
          float pv = exp2f(S[nt][r] - mnew);
          pr[nt][r] = pv;
          sum += pv;
        }
        lrun[r] = lrun[r] * alpha + sum;
#pragma unroll
        for (int ot = 0; ot < 8; ot++) O[ot][r] *= alpha;
      }

      // O += P V in two 32-key halves; per-kh Pl regions (no WAR stall).
#pragma unroll
      for (int kh = 0; kh < 2; kh++) {
#pragma unroll
        for (int nt = 0; nt < 2; nt++)
#pragma unroll
          for (int r = 0; r < 4; r++)
            Pl[wave][kh][quad * 4 + r][nt * 16 + l15] = f2bf(pr[kh * 2 + nt][r]);
        bf16x8 pf = *(const bf16x8*)&Pl[wave][kh][l15][quad * 8];
        __builtin_amdgcn_s_setprio(1);
#pragma unroll
        for (int ot = 0; ot < 8; ot++) {
          int dcol = ot * 16 + l15;
          bf16x8 vf = *(const bf16x8*)&Vt[dcol][(kh * 32 + quad * 8) ^ (vperm(dcol) << 3)];
          O[ot] = __builtin_amdgcn_mfma_f32_16x16x32_bf16(pf, vf, O[ot], 0, 0, 0);
        }
        __builtin_amdgcn_s_setprio(0);
      }
    }
  }

  // epilogue: finish the deferred cross-lane l reduction, then write
  const int t_out = m0 + w4 * 16 + quad * 4;
#pragma unroll
  for (int r = 0; r < 4; r++) {
    float s = lrun[r];
#pragma unroll
    for (int off = 1; off < 16; off <<= 1)
      s += __shfl_xor(s, off, 64);
    float inv_l = 1.f / s;
    us* yrow = y + (size_t)(b * T_SEQ + t_out + r) * D_MODEL + h * HD;
#pragma unroll
    for (int ot = 0; ot < 8; ot++)
      yrow[ot * 16 + l15] = f2bf(O[ot][r] * inv_l);
  }
}

// ---------------------------------------------------------------------------
extern "C" void kernel_launch(void* const* d_in, const int* in_sizes, int n_in,
                              void* d_out, int out_size, void* d_ws, size_t ws_size,
                              hipStream_t stream) {
  const float* x     = (const float*)d_in[0];  // [2,2048,2048] fp32
  const float* Wq    = (const float*)d_in[1];  // [2048,2048]
  const float* Wkv   = (const float*)d_in[2];  // [1024,2048]
  const float* Wproj = (const float*)d_in[3];  // [2048,2048]
  float* out = (float*)d_out;                  // [2,2048,2048] fp32

  const size_t NX  = (size_t)4096 * 2048;
  const size_t NWQ = (size_t)2048 * 2048;
  const size_t NWK = (size_t)1024 * 2048;
  const size_t needed_ws = (NX + (NWQ + NWK) + NWQ + NX) * sizeof(us);

  int b0 = (n_in >= 1 && (size_t)in_sizes[0] == NX);
  int b1 = (n_in >= 2 && (size_t)in_sizes[1] == NWQ);
  int b2 = (n_in >= 3 && (size_t)in_sizes[2] == NWK);
  int b3 = (n_in >= 4 && (size_t)in_sizes[3] == NWQ);
  int ws_ok = (ws_size >= needed_ws);
  int out_ok = ((size_t)out_size == NX);
  if (!(n_in == 4 && b0 && b1 && b2 && b3 && ws_ok && out_ok)) {
    float code = 1.0e6f * (float)(n_in < 10 ? n_in : 9)
               + 1.0e5f * b0 + 1.0e4f * b1 + 1.0e3f * b2 + 1.0e2f * b3
               + 10.0f * ws_ok + 40.0f * out_ok;
    fill_diag<<<dim3((out_size + 255) / 256), dim3(256), 0, stream>>>(out, code, out_size);
    return;
  }

  us* xb     = (us*)d_ws;
  us* Wqkvb  = xb + NX;            // [3072][2048]: rows 0-2047 Wq, 2048-3071 Wkv
  us* Wpb    = Wqkvb + NWQ + NWK;
  us* ybuf   = Wpb + NWQ;
  us* qkvbuf = (us*)d_out;         // bf16 qkv parks in d_out; dead before proj

  dim3 blk(256);
  cast_f32_bf16<<<dim3((int)(NX  / 8 / 256)), blk, 0, stream>>>(x,     xb,          (int)(NX  / 8));
  cast_f32_bf16<<<dim3((int)(NWQ / 8 / 256)), blk, 0, stream>>>(Wq,    Wqkvb,       (int)(NWQ / 8));
  cast_f32_bf16<<<dim3((int)(NWK / 8 / 256)), blk, 0, stream>>>(Wkv,   Wqkvb + NWQ, (int)(NWK / 8));
  cast_f32_bf16<<<dim3((int)(NWQ / 8 / 256)), blk, 0, stream>>>(Wproj, Wpb,         (int)(NWQ / 8));

  // qkv GEMM: 8-phase 256^2 (192 blocks, 75% fill -- per-CU faster, R11 -7us)
  gemm_bt8<us><<<dim3(16, 12), dim3(512), 0, stream>>>(xb, Wqkvb, qkvbuf, 4096, 3072, 2048);
  rope_kernel<<<dim3(4096), blk, 0, stream>>>(qkvbuf);
  // attn: 4-tile merge, 1024 threads, 1 block/CU (grid 8x32 = 256)
  attn_kernel<<<dim3(8, 32), dim3(1024), 0, stream>>>(qkvbuf, ybuf);
  // proj GEMM: 2-phase 128^2 (512 blocks, full fill)
  gemm_bt<float><<<dim3(32, 16), blk, 0, stream>>>(ybuf, Wpb, out, 4096, 2048, 2048);
}

// Round 15
// 330.882 us; speedup vs baseline: 1.3351x; 1.0236x over previous
//
#include <hip/hip_runtime.h>
#include <stdint.h>

#define T_SEQ 2048
#define D_MODEL 2048
#define N_KV 4
#define HD 128
#define QKV_W 3072   // fused row width: 2048 q | 512 k | 512 v

typedef unsigned short us;
typedef __attribute__((ext_vector_type(8))) short bf16x8;
typedef __attribute__((ext_vector_type(4))) float f32x4;
typedef __attribute__((ext_vector_type(8))) unsigned short u16x8;

__device__ __forceinline__ us f2bf(float f) {
  union { float f; unsigned int u; } v; v.f = f;
  unsigned int r = v.u + 0x7FFFu + ((v.u >> 16) & 1u);
  return (us)(r >> 16);
}
__device__ __forceinline__ float bf2f(us h) {
  union { unsigned int u; float f; } v; v.u = ((unsigned int)h) << 16;
  return v.f;
}

__device__ __forceinline__ void load_lds16(const void* g, void* l) {
  __builtin_amdgcn_global_load_lds(
      (const __attribute__((address_space(1))) void*)g,
      (__attribute__((address_space(3))) void*)l, 16, 0, 0);
}

__global__ void fill_diag(float* __restrict__ out, float val, int n) {
  int i = blockIdx.x * blockDim.x + threadIdx.x;
  if (i < n) out[i] = val;
}

// ---------------------------------------------------------------------------
__global__ void cast_f32_bf16(const float* __restrict__ src,
                              us* __restrict__ dst, int n8) {
  int i = blockIdx.x * blockDim.x + threadIdx.x;
  if (i >= n8) return;
  const float4* s = (const float4*)src + (size_t)i * 2;
  float4 a = s[0], b = s[1];
  u16x8 o;
  o[0] = f2bf(a.x); o[1] = f2bf(a.y); o[2] = f2bf(a.z); o[3] = f2bf(a.w);
  o[4] = f2bf(b.x); o[5] = f2bf(b.y); o[6] = f2bf(b.z); o[7] = f2bf(b.w);
  *((u16x8*)dst + i) = o;
}

#define GBAR()                                  \
  do {                                          \
    asm volatile("" ::: "memory");              \
    __builtin_amdgcn_s_barrier();               \
    asm volatile("" ::: "memory");              \
  } while (0)
#define VMCNT6() asm volatile("s_waitcnt vmcnt(6)" ::: "memory")
#define VMCNT4() asm volatile("s_waitcnt vmcnt(4)" ::: "memory")
#define VMCNT0() asm volatile("s_waitcnt vmcnt(0)" ::: "memory")

// ---------------------------------------------------------------------------
// 8-phase 256x256 GEMM (R10/R11-verified). Used for qkv GEMM (192 blocks,
// 75% fill; per-CU 2.56 TF vs 2-phase 1.87).
// ---------------------------------------------------------------------------
template <typename OUT>
__global__ __launch_bounds__(512) void gemm_bt8(
    const us* __restrict__ A, const us* __restrict__ B,
    OUT* __restrict__ C, int M, int N, int K) {
  __shared__ us As[2][16384];
  __shared__ us Bs[2][16384];

  const int tid  = threadIdx.x;
  const int lane = tid & 63;
  const int wave = tid >> 6;
  const int wm   = wave & 1;
  const int wn   = wave >> 1;
  const int l15  = lane & 15;
  const int quad = lane >> 4;
  const int bm = blockIdx.x * 256;
  const int bn = blockIdx.y * 256;
  const int wm8 = wm * 8;
  const int wn4 = wn * 4;

  const int ro = ((l15 << 5) | (quad << 3)) ^ ((l15 & 8) << 1);

  const int s    = lane ^ ((lane & 32) >> 4);
  const int srow = s >> 2;
  const int schk = (s & 3) * 8;

  const int R_Ae = (wave & 3) | ((wave & 4) << 1);
  const int R_Al = R_Ae + 4;
  const int R_Be = ((wave >> 1) << 2) | (wave & 1);
  const int R_Bl = R_Be + 2;

  const us* Ab = A + (size_t)bm * K;
  const us* Bb = B + (size_t)bn * K;

  f32x4 acc[8][4];
#pragma unroll
  for (int i = 0; i < 8; i++)
#pragma unroll
    for (int j = 0; j < 4; j++) acc[i][j] = (f32x4)0.f;

  bf16x8 af[4][2], bf[4][2];

#define STG(DST, PG, R, KT)                                                   \
  do {                                                                        \
    load_lds16((PG) + (size_t)((R) * 16 + srow) * K + (KT) * 64 + schk,       \
               &(DST)[(((R) * 2 + 0) << 9) + (lane << 3)]);                   \
    load_lds16((PG) + (size_t)((R) * 16 + srow) * K + (KT) * 64 + 32 + schk,  \
               &(DST)[(((R) * 2 + 1) << 9) + (lane << 3)]);                   \
  } while (0)

#define LDA4(BUF, MTB)                                                        \
  _Pragma("unroll") for (int t = 0; t < 4; t++)                               \
      _Pragma("unroll") for (int ks = 0; ks < 2; ks++)                        \
          af[t][ks] = *(const bf16x8*)&As[BUF][(((wm8 + (MTB) + t) * 2 + ks)  \
                                               << 9) + ro];

#define LDB2(BUF, NTB)                                                        \
  _Pragma("unroll") for (int t = 0; t < 2; t++)                               \
      _Pragma("unroll") for (int ks = 0; ks < 2; ks++)                        \
          bf[(NTB) + t][ks] = *(const bf16x8*)&Bs[BUF][                       \
              (((wn4 + (NTB) + t) * 2 + ks) << 9) + ro];

#define MQ(MH, NB)                                                            \
  __builtin_amdgcn_s_setprio(1);                                              \
  _Pragma("unroll") for (int t = 0; t < 4; t++)                               \
      _Pragma("unroll") for (int u = 0; u < 2; u++)                           \
          _Pragma("unroll") for (int ks = 0; ks < 2; ks++)                    \
              acc[(MH) * 4 + t][(NB) + u] =                                   \
                  __builtin_amdgcn_mfma_f32_16x16x32_bf16(                    \
                      af[t][ks], bf[(NB) + u][ks],                            \
                      acc[(MH) * 4 + t][(NB) + u], 0, 0, 0);                  \
  __builtin_amdgcn_s_setprio(0);

  STG(As[0], Ab, R_Ae, 0); STG(As[0], Ab, R_Al, 0);
  STG(Bs[0], Bb, R_Be, 0); STG(Bs[0], Bb, R_Bl, 0);
  STG(As[1], Ab, R_Ae, 1); STG(Bs[1], Bb, R_Be, 1); STG(Bs[1], Bb, R_Bl, 1);
  VMCNT6();
  GBAR();

  const int NI = K >> 7;
  for (int i = 0; i < NI - 1; i++) {
    const int t0 = 2 * i;
    LDA4(0, 0) LDB2(0, 0)
    STG(As[1], Ab, R_Al, t0 + 1);
    GBAR(); MQ(0, 0) GBAR();
    LDB2(0, 2)
    STG(As[0], Ab, R_Ae, t0 + 2);
    GBAR(); MQ(0, 2) GBAR();
    LDA4(0, 4)
    STG(Bs[0], Bb, R_Be, t0 + 2);
    GBAR(); MQ(1, 2) GBAR();
    STG(Bs[0], Bb, R_Bl, t0 + 2);
    GBAR(); MQ(1, 0) VMCNT6(); GBAR();
    LDA4(1, 0) LDB2(1, 0)
    STG(As[0], Ab, R_Al, t0 + 2);
    GBAR(); MQ(0, 0) GBAR();
    LDB2(1, 2)
    STG(As[1], Ab, R_Ae, t0 + 3);
    GBAR(); MQ(0, 2) GBAR();
    LDA4(1, 4)
    STG(Bs[1], Bb, R_Be, t0 + 3);
    GBAR(); MQ(1, 2) GBAR();
    STG(Bs[1], Bb, R_Bl, t0 + 3);
    GBAR(); MQ(1, 0) VMCNT6(); GBAR();
  }
  {
    const int t0 = 2 * NI - 2;
    LDA4(0, 0) LDB2(0, 0)
    STG(As[1], Ab, R_Al, t0 + 1);
    GBAR(); MQ(0, 0) GBAR();
    LDB2(0, 2)
    GBAR(); MQ(0, 2) GBAR();
    LDA4(0, 4)
    GBAR(); MQ(1, 2) GBAR();
    GBAR(); MQ(1, 0) VMCNT0(); GBAR();
    LDA4(1, 0) LDB2(1, 0)
    GBAR(); MQ(0, 0) GBAR();
    LDB2(1, 2)
    GBAR(); MQ(0, 2) GBAR();
    LDA4(1, 4)
    GBAR(); MQ(1, 2) GBAR();
    MQ(1, 0)
  }
#undef STG
#undef LDA4
#undef LDB2
#undef MQ

#pragma unroll
  for (int mt = 0; mt < 8; mt++) {
    int row = bm + wm * 128 + mt * 16 + quad * 4;
#pragma unroll
    for (int nt = 0; nt < 4; nt++) {
      int col = bn + wn * 64 + nt * 16 + l15;
#pragma unroll
      for (int r = 0; r < 4; r++) {
        if constexpr (sizeof(OUT) == 4)
          C[(size_t)(row + r) * N + col] = acc[mt][nt][r];
        else
          C[(size_t)(row + r) * N + col] = f2bf(acc[mt][nt][r]);
      }
    }
  }
}

// ---------------------------------------------------------------------------
// 8-phase 256x128 GEMM -- full-fill variant for the proj GEMM (N=2048 ->
// grid 16x16 = 256 blocks = exactly 1/CU; the 256^2 tile gave 128 blocks =
// half the machine idle, R10 +33us). Minimal delta from the verified 256^2
// schedule: B is 8 subtiles -> ONE stage group (R_B = wave); 3 groups/tile.
// Ledger: steady flight/wave = {t+1:Ae,B}=4; P1 +Al(t+1)->6; P2 +Ae(t+2)->8;
// P3 +B(t+2)->10; P4 drain vmcnt(4) completes t+1 (oldest 6), leaves
// {t+2:Ae,B}. P5-P8 mirror. Prologue: 10 in flight, vmcnt(4) -> tile0 done.
// WAR: Ae read@P1, staged@P2; Al read@P3, staged@P5; B read@P1/P2, staged@P3
// -- each last-read completes >=1 barrier before stage issue (same argument
// as the 256^2 kernel, verified twice on HW).
// ---------------------------------------------------------------------------
template <typename OUT>
__global__ __launch_bounds__(512) void gemm_bt8b(
    const us* __restrict__ A, const us* __restrict__ B,
    OUT* __restrict__ C, int M, int N, int K) {
  __shared__ us As[2][16384];   // 256 rows x 64 K
  __shared__ us Bs[2][8192];    // 128 rows x 64 K

  const int tid  = threadIdx.x;
  const int lane = tid & 63;
  const int wave = tid >> 6;          // 0..7
  const int wm   = wave & 1;          // M-half (128 rows)
  const int wn   = wave >> 1;         // N-quarter (32 cols)
  const int l15  = lane & 15;
  const int quad = lane >> 4;
  const int bm = blockIdx.x * 256;
  const int bn = blockIdx.y * 128;
  const int wm8 = wm * 8;
  const int wn2 = wn * 2;

  const int ro = ((l15 << 5) | (quad << 3)) ^ ((l15 & 8) << 1);

  const int s    = lane ^ ((lane & 32) >> 4);
  const int srow = s >> 2;
  const int schk = (s & 3) * 8;

  const int R_Ae = (wave & 3) | ((wave & 4) << 1);   // {0..3, 8..11}
  const int R_Al = R_Ae + 4;                         // {4..7, 12..15}
  const int R_B  = wave;                             // 0..7 (all of B)

  const us* Ab = A + (size_t)bm * K;
  const us* Bb = B + (size_t)bn * K;

  f32x4 acc[8][2];
#pragma unroll
  for (int i = 0; i < 8; i++)
#pragma unroll
    for (int j = 0; j < 2; j++) acc[i][j] = (f32x4)0.f;

  bf16x8 af[4][2], bf[2][2];

#define STGB(DST, PG, R, KT)                                                  \
  do {                                                                        \
    load_lds16((PG) + (size_t)((R) * 16 + srow) * K + (KT) * 64 + schk,       \
               &(DST)[(((R) * 2 + 0) << 9) + (lane << 3)]);                   \
    load_lds16((PG) + (size_t)((R) * 16 + srow) * K + (KT) * 64 + 32 + schk,  \
               &(DST)[(((R) * 2 + 1) << 9) + (lane << 3)]);                   \
  } while (0)

#define LDA4B(BUF, MTB)                                                       \
  _Pragma("unroll") for (int t = 0; t < 4; t++)                               \
      _Pragma("unroll") for (int ks = 0; ks < 2; ks++)                        \
          af[t][ks] = *(const bf16x8*)&As[BUF][(((wm8 + (MTB) + t) * 2 + ks)  \
                                               << 9) + ro];

#define LDB1B(BUF, NT)                                                        \
  _Pragma("unroll") for (int ks = 0; ks < 2; ks++)                            \
      bf[NT][ks] = *(const bf16x8*)&Bs[BUF][(((wn2 + (NT)) * 2 + ks) << 9) +  \
                                            ro];

#define MQB(MH, NB)                                                           \
  __builtin_amdgcn_s_setprio(1);                                              \
  _Pragma("unroll") for (int t = 0; t < 4; t++)                               \
      _Pragma("unroll") for (int ks = 0; ks < 2; ks++)                        \
          acc[(MH) * 4 + t][NB] =                                             \
              __builtin_amdgcn_mfma_f32_16x16x32_bf16(                        \
                  af[t][ks], bf[NB][ks], acc[(MH) * 4 + t][NB], 0, 0, 0);     \
  __builtin_amdgcn_s_setprio(0);

  // prologue: tile0 {Ae,Al,B}, tile1 {Ae,B}; flight 10; vmcnt(4)->tile0 done
  STGB(As[0], Ab, R_Ae, 0); STGB(As[0], Ab, R_Al, 0); STGB(Bs[0], Bb, R_B, 0);
  STGB(As[1], Ab, R_Ae, 1); STGB(Bs[1], Bb, R_B, 1);
  VMCNT4();
  GBAR();

  const int NI = K >> 7;
  for (int i = 0; i < NI - 1; i++) {
    const int t0 = 2 * i;
    // P1
    LDA4B(0, 0) LDB1B(0, 0)
    STGB(As[1], Ab, R_Al, t0 + 1);
    GBAR(); MQB(0, 0) GBAR();
    // P2
    LDB1B(0, 1)
    STGB(As[0], Ab, R_Ae, t0 + 2);
    GBAR(); MQB(0, 1) GBAR();
    // P3
    LDA4B(0, 4)
    STGB(Bs[0], Bb, R_B, t0 + 2);
    GBAR(); MQB(1, 1) GBAR();
    // P4
    GBAR(); MQB(1, 0) VMCNT4(); GBAR();
    // P5
    LDA4B(1, 0) LDB1B(1, 0)
    STGB(As[0], Ab, R_Al, t0 + 2);
    GBAR(); MQB(0, 0) GBAR();
    // P6
    LDB1B(1, 1)
    STGB(As[1], Ab, R_Ae, t0 + 3);
    GBAR(); MQB(0, 1) GBAR();
    // P7
    LDA4B(1, 4)
    STGB(Bs[1], Bb, R_B, t0 + 3);
    GBAR(); MQB(1, 1) GBAR();
    // P8
    GBAR(); MQB(1, 0) VMCNT4(); GBAR();
  }
  // peeled last iteration: only Al(t+1) remains to stage; drain全 at P4
  {
    LDA4B(0, 0) LDB1B(0, 0)
    STGB(As[1], Ab, R_Al, 2 * NI - 1);
    GBAR(); MQB(0, 0) GBAR();
    LDB1B(0, 1)
    GBAR(); MQB(0, 1) GBAR();
    LDA4B(0, 4)
    GBAR(); MQB(1, 1) GBAR();
    GBAR(); MQB(1, 0) VMCNT0(); GBAR();
    LDA4B(1, 0) LDB1B(1, 0)
    GBAR(); MQB(0, 0) GBAR();
    LDB1B(1, 1)
    GBAR(); MQB(0, 1) GBAR();
    LDA4B(1, 4)
    GBAR(); MQB(1, 1) GBAR();
    MQB(1, 0)
  }
#undef STGB
#undef LDA4B
#undef LDB1B
#undef MQB

#pragma unroll
  for (int mt = 0; mt < 8; mt++) {
    int row = bm + wm * 128 + mt * 16 + quad * 4;
#pragma unroll
    for (int nt = 0; nt < 2; nt++) {
      int col = bn + wn * 32 + nt * 16 + l15;
#pragma unroll
      for (int r = 0; r < 4; r++) {
        if constexpr (sizeof(OUT) == 4)
          C[(size_t)(row + r) * N + col] = acc[mt][nt][r];
        else
          C[(size_t)(row + r) * N + col] = f2bf(acc[mt][nt][r]);
      }
    }
  }
}

// ---------------------------------------------------------------------------
// RoPE in-place on fused qkv [B*T][3072].
// ---------------------------------------------------------------------------
__global__ void rope_kernel(us* __restrict__ qkv) {
  const int row = blockIdx.x;
  const int t = row & (T_SEQ - 1);
  const int tid = threadIdx.x;
  const float L2_10K_64 = 13.287712379549449f / 64.f;
  us* rp = qkv + (size_t)row * QKV_W;

#pragma unroll
  for (int it = 0; it < 4; it++) {
    int idx = it * 256 + tid;
    int h = idx >> 6, i = idx & 63;
    int base = h * HD;
    float ang = (float)t * exp2f(-(float)i * L2_10K_64);
    float s, c; sincosf(ang, &s, &c);
    float x1 = bf2f(rp[base + i]);
    float x2 = bf2f(rp[base + i + 64]);
    rp[base + i]      = f2bf(x1 * c - x2 * s);
    rp[base + i + 64] = f2bf(x2 * c + x1 * s);
  }
  {
    int h = tid >> 6, i = tid & 63;
    int base = 2048 + h * HD;
    float ang = (float)t * exp2f(-(float)i * L2_10K_64);
    float s, c; sincosf(ang, &s, &c);
    float x1 = bf2f(rp[base + i]);
    float x2 = bf2f(rp[base + i + 64]);
    rp[base + i]      = f2bf(x1 * c - x2 * s);
    rp[base + i + 64] = f2bf(x2 * c + x1 * s);
  }
}

// ---------------------------------------------------------------------------
// Causal flash attention, GQA -- FOUR-tile merge (R14: 108us, occupancy 41%)
// + T13 defer-max: skip the O-rescale/alpha chain when per-chunk max growth
// <= 8 (base-2; P bounded by 2^8, bf16-safe). VALUBusy was 39% vs MfmaUtil
// 13.5% -- softmax VALU dominates; rescale is its biggest slice.
// ---------------------------------------------------------------------------
__device__ __forceinline__ int vperm(int d) { return ((d >> 3) ^ d) & 7; }

__global__ __launch_bounds__(1024) void attn_kernel(
    const us* __restrict__ qkv, us* __restrict__ y) {
  __shared__ us Ks[64][136];
  __shared__ us Vt[128][64];
  __shared__ us Pl[16][2][16][40];

  const int tid  = threadIdx.x;
  const int lane = tid & 63;
  const int wave = tid >> 6;           // 0..15
  const int l15  = lane & 15;
  const int quad = lane >> 4;
  const int bh = blockIdx.y;
  const int b  = bh >> 4;
  const int h  = bh & 15;
  const int hk = h >> 2;
  const int p  = blockIdx.x;           // 0..7
  const int g  = wave >> 2;            // tile group 0..3
  const int w4 = wave & 3;
  const int xA = 31 - p;
  const int x_mine = (g == 0) ? (31 - p)
                   : (g == 1) ? p
                   : (g == 2) ? (15 - p)
                              : (16 + p);
  const int m0 = x_mine * 64;

  const us* base = qkv + (size_t)b * T_SEQ * QKV_W;
  const int kcol = 2048 + hk * HD;
  const int vcol = kcol + 512;
  const int skey = tid >> 4;           // 0..63
  const int skk  = (tid & 15) * 8;
  const float scale = 0.12751744f;     // 1/sqrt(128) * log2(e)

  bf16x8 qf[4];
  {
    const us* Qrow = base + (size_t)(m0 + w4 * 16 + l15) * QKV_W + h * HD;
#pragma unroll
    for (int s = 0; s < 4; s++)
      qf[s] = *(const bf16x8*)&Qrow[s * 32 + quad * 8];
  }

  f32x4 O[8];
#pragma unroll
  for (int i = 0; i < 8; i++) O[i] = (f32x4)0.f;
  float mrun[4], lrun[4];
#pragma unroll
  for (int r = 0; r < 4; r++) { mrun[r] = -INFINITY; lrun[r] = 0.f; }

  uint4 kreg; u16x8 vreg;
  {
    const us* row = base + (size_t)skey * QKV_W;
    kreg = *(const uint4*)(row + kcol + skk);
    vreg = *(const u16x8*)(row + vcol + skk);
  }

  for (int j = 0; j <= xA; j++) {
    __syncthreads();
    *(uint4*)&Ks[skey][skk] = kreg;
#pragma unroll
    for (int i = 0; i < 8; i++) {
      int d = skk + i;
      Vt[d][skey ^ (vperm(d) << 3)] = vreg[i];
    }
    __syncthreads();

    if (j < xA) {
      const us* row = base + (size_t)((j + 1) * 64 + skey) * QKV_W;
      kreg = *(const uint4*)(row + kcol + skk);
      vreg = *(const u16x8*)(row + vcol + skk);
    }

    if (j <= x_mine) {               // wave-uniform guard; barriers outside
      // S = Q K^T
      f32x4 S[4];
      __builtin_amdgcn_s_setprio(1);
#pragma unroll
      for (int nt = 0; nt < 4; nt++) {
        f32x4 sa = (f32x4)0.f;
#pragma unroll
        for (int ks = 0; ks < 4; ks++) {
          bf16x8 kf = *(const bf16x8*)&Ks[nt * 16 + l15][ks * 32 + quad * 8];
          sa = __builtin_amdgcn_mfma_f32_16x16x32_bf16(qf[ks], kf, sa, 0, 0, 0);
        }
        S[nt] = sa;
      }
      __builtin_amdgcn_s_setprio(0);

      const int row0 = m0 + w4 * 16 + quad * 4;
      if (j == x_mine) {
        const int k0 = j * 64;
#pragma unroll
        for (int nt = 0; nt < 4; nt++) {
          int col = k0 + nt * 16 + l15;
#pragma unroll
          for (int r = 0; r < 4; r++) {
            float v = S[nt][r] * scale;
            if (col > row0 + r) v = -INFINITY;
            S[nt][r] = v;
          }
        }
      } else {
#pragma unroll
        for (int nt = 0; nt < 4; nt++)
#pragma unroll
          for (int r = 0; r < 4; r++) S[nt][r] *= scale;
      }

      // online softmax (base 2) + T13 defer-max: keep the old running max
      // when the chunk max grew by <= 8 -- skips alpha/exp2 + 32 O-mults.
      // First chunk: mrun=-inf -> growth=+inf -> rescale path (alpha=0).
      float mx[4];
#pragma unroll
      for (int r = 0; r < 4; r++) {
        float m = fmaxf(fmaxf(S[0][r], S[1][r]), fmaxf(S[2][r], S[3][r]));
#pragma unroll
        for (int off = 1; off < 16; off <<= 1)
          m = fmaxf(m, __shfl_xor(m, off, 64));
        mx[r] = m;
      }
      float growth = fmaxf(fmaxf(mx[0] - mrun[0], mx[1] - mrun[1]),
                           fmaxf(mx[2] - mrun[2], mx[3] - mrun[3]));
      if (!__all(growth <= 8.f)) {
#pragma unroll
        for (int r = 0; r < 4; r++) {
          float mnew = fmaxf(mrun[r], mx[r]);
          float alpha = exp2f(mrun[r] - mnew);
          mrun[r] = mnew;
          lrun[r] *= alpha;
#pragma unroll
          for (int ot = 0; ot < 8; ot++) O[ot][r] *= alpha;
        }
      }
      float pr[4][4];
#pragma unroll
      for (int r = 0; r < 4; r++) {
        float sum = 0.f;
#pragma unroll
        for (int nt = 0; nt < 4; nt++) {
          float pv = exp2f(S[nt][r] - mrun[r]);
          pr[nt][r] = pv;
          sum += pv;
        }
        lrun[r] += sum;
      }

      // O += P V in two 32-key halves; per-kh Pl regions (no WAR stall).
#pragma unroll
      for (int kh = 0; kh < 2; kh++) {
#pragma unroll
        for (int nt = 0; nt < 2; nt++)
#pragma unroll
          for (int r = 0; r < 4; r++)
            Pl[wave][kh][quad * 4 + r][nt * 16 + l15] = f2bf(pr[kh * 2 + nt][r]);
        bf16x8 pf = *(const bf16x8*)&Pl[wave][kh][l15][quad * 8];
        __builtin_amdgcn_s_setprio(1);
#pragma unroll
        for (int ot = 0; ot < 8; ot++) {
          int dcol = ot * 16 + l15;
          bf16x8 vf = *(const bf16x8*)&Vt[dcol][(kh * 32 + quad * 8) ^ (vperm(dcol) << 3)];
          O[ot] = __builtin_amdgcn_mfma_f32_16x16x32_bf16(pf, vf, O[ot], 0, 0, 0);
        }
        __builtin_amdgcn_s_setprio(0);
      }
    }
  }

  // epilogue: finish the deferred cross-lane l reduction, then write
  const int t_out = m0 + w4 * 16 + quad * 4;
#pragma unroll
  for (int r = 0; r < 4; r++) {
    float s = lrun[r];
#pragma unroll
    for (int off = 1; off < 16; off <<= 1)
      s += __shfl_xor(s, off, 64);
    float inv_l = 1.f / s;
    us* yrow = y + (size_t)(b * T_SEQ + t_out + r) * D_MODEL + h * HD;
#pragma unroll
    for (int ot = 0; ot < 8; ot++)
      yrow[ot * 16 + l15] = f2bf(O[ot][r] * inv_l);
  }
}

// ---------------------------------------------------------------------------
extern "C" void kernel_launch(void* const* d_in, const int* in_sizes, int n_in,
                              void* d_out, int out_size, void* d_ws, size_t ws_size,
                              hipStream_t stream) {
  const float* x     = (const float*)d_in[0];  // [2,2048,2048] fp32
  const float* Wq    = (const float*)d_in[1];  // [2048,2048]
  const float* Wkv   = (const float*)d_in[2];  // [1024,2048]
  const float* Wproj = (const float*)d_in[3];  // [2048,2048]
  float* out = (float*)d_out;                  // [2,2048,2048] fp32

  const size_t NX  = (size_t)4096 * 2048;
  const size_t NWQ = (size_t)2048 * 2048;
  const size_t NWK = (size_t)1024 * 2048;
  const size_t needed_ws = (NX + (NWQ + NWK) + NWQ + NX) * sizeof(us);

  int b0 = (n_in >= 1 && (size_t)in_sizes[0] == NX);
  int b1 = (n_in >= 2 && (size_t)in_sizes[1] == NWQ);
  int b2 = (n_in >= 3 && (size_t)in_sizes[2] == NWK);
  int b3 = (n_in >= 4 && (size_t)in_sizes[3] == NWQ);
  int ws_ok = (ws_size >= needed_ws);
  int out_ok = ((size_t)out_size == NX);
  if (!(n_in == 4 && b0 && b1 && b2 && b3 && ws_ok && out_ok)) {
    float code = 1.0e6f * (float)(n_in < 10 ? n_in : 9)
               + 1.0e5f * b0 + 1.0e4f * b1 + 1.0e3f * b2 + 1.0e2f * b3
               + 10.0f * ws_ok + 40.0f * out_ok;
    fill_diag<<<dim3((out_size + 255) / 256), dim3(256), 0, stream>>>(out, code, out_size);
    return;
  }

  us* xb     = (us*)d_ws;
  us* Wqkvb  = xb + NX;            // [3072][2048]: rows 0-2047 Wq, 2048-3071 Wkv
  us* Wpb    = Wqkvb + NWQ + NWK;
  us* ybuf   = Wpb + NWQ;
  us* qkvbuf = (us*)d_out;         // bf16 qkv parks in d_out; dead before proj

  dim3 blk(256);
  cast_f32_bf16<<<dim3((int)(NX  / 8 / 256)), blk, 0, stream>>>(x,     xb,          (int)(NX  / 8));
  cast_f32_bf16<<<dim3((int)(NWQ / 8 / 256)), blk, 0, stream>>>(Wq,    Wqkvb,       (int)(NWQ / 8));
  cast_f32_bf16<<<dim3((int)(NWK / 8 / 256)), blk, 0, stream>>>(Wkv,   Wqkvb + NWQ, (int)(NWK / 8));
  cast_f32_bf16<<<dim3((int)(NWQ / 8 / 256)), blk, 0, stream>>>(Wproj, Wpb,         (int)(NWQ / 8));

  // qkv GEMM: 8-phase 256^2 (192 blocks, 75% fill)
  gemm_bt8<us><<<dim3(16, 12), dim3(512), 0, stream>>>(xb, Wqkvb, qkvbuf, 4096, 3072, 2048);
  rope_kernel<<<dim3(4096), blk, 0, stream>>>(qkvbuf);
  // attn: 4-tile merge + defer-max (grid 8x32 = 256 blocks, 1/CU)
  attn_kernel<<<dim3(8, 32), dim3(1024), 0, stream>>>(qkvbuf, ybuf);
  // proj GEMM: 8-phase 256x128 (grid 16x16 = 256 blocks, FULL fill)
  gemm_bt8b<float><<<dim3(16, 16), dim3(512), 0, stream>>>(ybuf, Wpb, out, 4096, 2048, 2048);
}